// Round 1
// baseline (2222.702 us; speedup 1.0000x reference)
//
#include <hip/hip_runtime.h>
#include <hip/hip_bf16.h>

// Problem constants (match reference)
#define E_LINKS 131072
#define M_PAIRS 1048576
#define DDIM    64
#define GG      1024
#define RUNITS  256
#define TITER   8

typedef __attribute__((ext_vector_type(8))) short bf16x8;
typedef __attribute__((ext_vector_type(4))) float f32x4;

__device__ inline unsigned short f2bf(float f){
  union { float f; unsigned int u; } v; v.f = f;
  unsigned int u = v.u;
  unsigned int r = (u + 0x7FFFu + ((u >> 16) & 1u)) >> 16;
  return (unsigned short)r;
}
__device__ inline float bf2f(unsigned short u){
  union { unsigned int u; float f; } v; v.u = ((unsigned int)u) << 16; return v.f;
}
__device__ inline float selu_f(float x){
  // lambda = 1.0507009873554805, lambda*alpha = 1.7580993408473766
  return x > 0.f ? 1.0507009873554805f * x
                 : 1.7580993408473766f * (__expf(x) - 1.f);
}
__device__ inline float sigmoid_f(float x){ return 1.f / (1.f + __expf(-x)); }
__device__ inline float tanh_f(float x){
  float xc = fminf(fmaxf(x, -15.f), 15.f);
  float e2 = __expf(2.f * xc);
  return (e2 - 1.f) / (e2 + 1.f);
}

// ---------------- preprocessing ----------------

__global__ void k_zero(int* __restrict__ counts, int* __restrict__ gcounts){
  int i = blockIdx.x * blockDim.x + threadIdx.x;
  if (i < E_LINKS) counts[i] = 0;
  if (i < GG) gcounts[i] = 0;
}

__global__ void k_hist(const int* __restrict__ second, int* __restrict__ counts){
  int i = blockIdx.x * blockDim.x + threadIdx.x;
  if (i < M_PAIRS) atomicAdd(&counts[second[i]], 1);
}

__global__ void k_ghist(const int* __restrict__ gid, int* __restrict__ gcounts){
  int i = blockIdx.x * blockDim.x + threadIdx.x;
  if (i < E_LINKS) atomicAdd(&gcounts[gid[i]], 1);
}

// single-block exclusive scan, n must be multiple of 1024
__global__ __launch_bounds__(1024) void k_scan(const int* __restrict__ counts,
    int* __restrict__ offsets, int* __restrict__ cursor, int n){
  __shared__ int part[1024];
  int t = threadIdx.x;
  int chunk = n >> 10;
  int base = t * chunk;
  int s = 0;
  for (int i = 0; i < chunk; i++) s += counts[base + i];
  part[t] = s; __syncthreads();
  for (int off = 1; off < 1024; off <<= 1){
    int v = (t >= off) ? part[t - off] : 0;
    __syncthreads();
    part[t] += v;
    __syncthreads();
  }
  int run = part[t] - s; // exclusive prefix
  for (int i = 0; i < chunk; i++){
    int c = counts[base + i];
    offsets[base + i] = run;
    if (cursor) cursor[base + i] = run;
    run += c;
  }
  if (t == 1023) offsets[n] = run;
}

__global__ void k_scatter(const int* __restrict__ first, const int* __restrict__ second,
    int* __restrict__ cursor, int* __restrict__ srcs){
  int i = blockIdx.x * blockDim.x + threadIdx.x;
  if (i < M_PAIRS){
    int e = second[i];
    int slot = atomicAdd(&cursor[e], 1);
    srcs[slot] = first[i];
  }
}

// Build transposed bf16 weights:
// WcT[c][k], c in [0,128): c<64 -> W_msg[k][c]; c>=64 -> W_msg[64+k][c-64]
// kT[c][k] = gru_kernel[k][c], rkT[c][k] = gru_rkernel[k][c]   (c in [0,192))
__global__ void k_prepw(const float* __restrict__ W_msg, const float* __restrict__ gk,
    const float* __restrict__ grk, unsigned short* __restrict__ WcT,
    unsigned short* __restrict__ kT, unsigned short* __restrict__ rkT){
  int i = blockIdx.x * blockDim.x + threadIdx.x;
  const int N1 = 128 * 64, N2 = 192 * 64;
  if (i < N1){
    int c = i >> 6, k = i & 63;
    float v = (c < 64) ? W_msg[k * 64 + c] : W_msg[(64 + k) * 64 + (c - 64)];
    WcT[i] = f2bf(v);
  } else if (i < N1 + N2){
    int j = i - N1; int c = j >> 6, k = j & 63;
    kT[j] = f2bf(gk[k * 192 + c]);
  } else if (i < N1 + 2 * N2){
    int j = i - N1 - N2; int c = j >> 6, k = j & 63;
    rkT[j] = f2bf(grk[k * 192 + c]);
  }
}

__global__ void k_init(const float* __restrict__ sa, float* __restrict__ hf,
                       unsigned short* __restrict__ hb){
  int i = blockIdx.x * blockDim.x + threadIdx.x; // E*64 threads
  float v = sa[i];
  hf[i] = v;
  hb[i] = f2bf(v);
}

// ---------------- main loop kernels ----------------

// AB[E,128] = h[E,64] @ Wc[64,128]  (+ b_msg on cols>=64), bf16 in/out, fp32 acc
__global__ __launch_bounds__(256) void k_ab(const unsigned short* __restrict__ hb,
    const unsigned short* __restrict__ WcT, const float* __restrict__ b_msg,
    unsigned short* __restrict__ AB){
  int wave = threadIdx.x >> 6, lane = threadIdx.x & 63;
  int row0 = (blockIdx.x * 4 + wave) * 16;
  int lr = lane & 15, lg = lane >> 4;
  f32x4 acc[8];
  #pragma unroll
  for (int i = 0; i < 8; i++) acc[i] = (f32x4){0.f, 0.f, 0.f, 0.f};
  #pragma unroll
  for (int s = 0; s < 2; s++){
    int kb = s * 32 + lg * 8;
    bf16x8 a = *(const bf16x8*)(hb + (size_t)(row0 + lr) * 64 + kb);
    #pragma unroll
    for (int ct = 0; ct < 8; ct++){
      bf16x8 b = *(const bf16x8*)(WcT + (ct * 16 + lr) * 64 + kb);
      acc[ct] = __builtin_amdgcn_mfma_f32_16x16x32_bf16(a, b, acc[ct], 0, 0, 0);
    }
  }
  #pragma unroll
  for (int ct = 0; ct < 8; ct++){
    int col = ct * 16 + lr;
    float bias = (col >= 64) ? b_msg[col - 64] : 0.f;
    #pragma unroll
    for (int q = 0; q < 4; q++){
      int row = row0 + lg * 4 + q;
      AB[(size_t)row * 128 + col] = f2bf(acc[ct][q] + bias);
    }
  }
}

// agg[e][:] = sum over incoming msgs: selu(A[src] + B[e])
__global__ __launch_bounds__(256) void k_agg(const unsigned short* __restrict__ AB,
    const int* __restrict__ offsets, const int* __restrict__ srcs,
    unsigned short* __restrict__ agg){
  int wave = threadIdx.x >> 6, lane = threadIdx.x & 63;
  int e = blockIdx.x * 4 + wave;
  float bv = bf2f(AB[(size_t)e * 128 + 64 + lane]);
  int beg = offsets[e], end = offsets[e + 1];
  float acc = 0.f;
  for (int i = beg; i < end; i++){
    int s = srcs[i];
    acc += selu_f(bf2f(AB[(size_t)s * 128 + lane]) + bv);
  }
  agg[(size_t)e * 64 + lane] = f2bf(acc);
}

// Fused GRU: mx = agg@k + bi, mh = h@rk + br, gates, in-place h update
__global__ __launch_bounds__(256) void k_gru(const unsigned short* __restrict__ agg,
    unsigned short* __restrict__ hb, float* __restrict__ hf,
    const unsigned short* __restrict__ kT, const unsigned short* __restrict__ rkT,
    const float* __restrict__ bi, const float* __restrict__ br){
  int wave = threadIdx.x >> 6, lane = threadIdx.x & 63;
  int row0 = (blockIdx.x * 4 + wave) * 16;
  int lr = lane & 15, lg = lane >> 4;
  f32x4 ax[12], ah[12];
  #pragma unroll
  for (int i = 0; i < 12; i++){ ax[i] = (f32x4){0.f,0.f,0.f,0.f}; ah[i] = (f32x4){0.f,0.f,0.f,0.f}; }
  #pragma unroll
  for (int s = 0; s < 2; s++){
    int kb = s * 32 + lg * 8;
    bf16x8 xa = *(const bf16x8*)(agg + (size_t)(row0 + lr) * 64 + kb);
    bf16x8 ha = *(const bf16x8*)(hb  + (size_t)(row0 + lr) * 64 + kb);
    #pragma unroll
    for (int ct = 0; ct < 12; ct++){
      bf16x8 bx = *(const bf16x8*)(kT + (ct * 16 + lr) * 64 + kb);
      ax[ct] = __builtin_amdgcn_mfma_f32_16x16x32_bf16(xa, bx, ax[ct], 0, 0, 0);
    }
    #pragma unroll
    for (int ct = 0; ct < 12; ct++){
      bf16x8 bh = *(const bf16x8*)(rkT + (ct * 16 + lr) * 64 + kb);
      ah[ct] = __builtin_amdgcn_mfma_f32_16x16x32_bf16(ha, bh, ah[ct], 0, 0, 0);
    }
  }
  #pragma unroll
  for (int jt = 0; jt < 4; jt++){
    int j = jt * 16 + lr;
    float biz = bi[j], bir = bi[64 + j], bih = bi[128 + j];
    float brz = br[j], brr = br[64 + j], brh = br[128 + j];
    #pragma unroll
    for (int q = 0; q < 4; q++){
      int row = row0 + lg * 4 + q;
      float xz = ax[jt][q] + biz,     hz = ah[jt][q] + brz;
      float xr = ax[4 + jt][q] + bir, hr = ah[4 + jt][q] + brr;
      float xh = ax[8 + jt][q] + bih, hh = ah[8 + jt][q] + brh;
      float z = sigmoid_f(xz + hz);
      float r = sigmoid_f(xr + hr);
      float c = tanh_f(xh + r * hh);
      size_t idx = (size_t)row * 64 + j;
      float hold = hf[idx];
      float hn = z * hold + (1.f - z) * c;
      hf[idx] = hn;
      hb[idx] = f2bf(hn);
    }
  }
}

// ---------------- readout ----------------

__global__ __launch_bounds__(256) void k_seg(const float* __restrict__ hf,
    const int* __restrict__ goff, float* __restrict__ gsum){
  int wave = threadIdx.x >> 6, lane = threadIdx.x & 63;
  int g = blockIdx.x * 4 + wave;
  int beg = goff[g], end = goff[g + 1];
  float acc = 0.f;
  for (int e = beg; e < end; e++) acc += hf[(size_t)e * 64 + lane];
  gsum[(size_t)g * 64 + lane] = acc;
}

__global__ __launch_bounds__(256) void k_mlp(const float* __restrict__ gsum,
    const float* __restrict__ W1, const float* __restrict__ b1,
    const float* __restrict__ W2, const float* __restrict__ b2,
    const float* __restrict__ W3, const float* __restrict__ b3,
    float* __restrict__ out){
  __shared__ float sg[64];
  __shared__ float sr1[256];
  __shared__ float sr2[256];
  __shared__ float wsum[4];
  int g = blockIdx.x, t = threadIdx.x;
  if (t < 64) sg[t] = gsum[(size_t)g * 64 + t];
  __syncthreads();
  float a = b1[t];
  #pragma unroll
  for (int k = 0; k < 64; k++) a += sg[k] * W1[k * 256 + t];
  sr1[t] = selu_f(a);
  __syncthreads();
  float b = b2[t];
  for (int k = 0; k < 256; k++) b += sr1[k] * W2[k * 256 + t];
  sr2[t] = selu_f(b);
  __syncthreads();
  float v = sr2[t] * W3[t];
  for (int off = 32; off > 0; off >>= 1) v += __shfl_down(v, off, 64);
  if ((t & 63) == 0) wsum[t >> 6] = v;
  __syncthreads();
  if (t == 0) out[g] = wsum[0] + wsum[1] + wsum[2] + wsum[3] + b3[0];
}

// ---------------- host ----------------

static inline size_t alignup(size_t x){ return (x + 255) & ~(size_t)255; }

extern "C" void kernel_launch(void* const* d_in, const int* in_sizes, int n_in,
                              void* d_out, int out_size, void* d_ws, size_t ws_size,
                              hipStream_t stream) {
  const float* states_action = (const float*)d_in[0];
  const int*   graph_ids     = (const int*)d_in[1];
  const int*   first         = (const int*)d_in[2];
  const int*   second        = (const int*)d_in[3];
  const float* W_msg         = (const float*)d_in[5];
  const float* b_msg         = (const float*)d_in[6];
  const float* gk            = (const float*)d_in[7];
  const float* grk           = (const float*)d_in[8];
  const float* bi            = (const float*)d_in[9];
  const float* br            = (const float*)d_in[10];
  const float* W1            = (const float*)d_in[11];
  const float* b1            = (const float*)d_in[12];
  const float* W2            = (const float*)d_in[13];
  const float* b2            = (const float*)d_in[14];
  const float* W3            = (const float*)d_in[15];
  const float* b3            = (const float*)d_in[16];
  float* out = (float*)d_out;

  char* ws = (char*)d_ws;
  size_t off = 0;
  float*          h_f32  = (float*)(ws + off);          off += alignup((size_t)E_LINKS * 64 * 4);
  unsigned short* h_bf   = (unsigned short*)(ws + off); off += alignup((size_t)E_LINKS * 64 * 2);
  unsigned short* aggb   = (unsigned short*)(ws + off); off += alignup((size_t)E_LINKS * 64 * 2);
  unsigned short* AB     = (unsigned short*)(ws + off); off += alignup((size_t)E_LINKS * 128 * 2);
  unsigned short* WcT    = (unsigned short*)(ws + off); off += alignup(128 * 64 * 2);
  unsigned short* kT     = (unsigned short*)(ws + off); off += alignup(192 * 64 * 2);
  unsigned short* rkT    = (unsigned short*)(ws + off); off += alignup(192 * 64 * 2);
  int*            counts = (int*)(ws + off);            off += alignup((size_t)E_LINKS * 4);
  int*            offs   = (int*)(ws + off);            off += alignup(((size_t)E_LINKS + 1) * 4);
  int*            cursor = (int*)(ws + off);            off += alignup((size_t)E_LINKS * 4);
  int*            srcs   = (int*)(ws + off);            off += alignup((size_t)M_PAIRS * 4);
  int*            gcnts  = (int*)(ws + off);            off += alignup((size_t)GG * 4);
  int*            goffs  = (int*)(ws + off);            off += alignup(((size_t)GG + 1) * 4);
  float*          gsum   = (float*)(ws + off);          off += alignup((size_t)GG * 64 * 4);

  dim3 b256(256);

  // CSR preprocessing
  k_zero<<<dim3(E_LINKS / 256), b256, 0, stream>>>(counts, gcnts);
  k_hist<<<dim3(M_PAIRS / 256), b256, 0, stream>>>(second, counts);
  k_ghist<<<dim3(E_LINKS / 256), b256, 0, stream>>>(graph_ids, gcnts);
  k_scan<<<dim3(1), dim3(1024), 0, stream>>>(counts, offs, cursor, E_LINKS);
  k_scan<<<dim3(1), dim3(1024), 0, stream>>>(gcnts, goffs, nullptr, GG);
  k_scatter<<<dim3(M_PAIRS / 256), b256, 0, stream>>>(first, second, cursor, srcs);

  // weights + h init
  k_prepw<<<dim3(128), b256, 0, stream>>>(W_msg, gk, grk, WcT, kT, rkT);
  k_init<<<dim3(E_LINKS * 64 / 256), b256, 0, stream>>>(states_action, h_f32, h_bf);

  // message passing
  for (int t = 0; t < TITER; t++){
    k_ab <<<dim3(E_LINKS / 64), b256, 0, stream>>>(h_bf, WcT, b_msg, AB);
    k_agg<<<dim3(E_LINKS / 4),  b256, 0, stream>>>(AB, offs, srcs, aggb);
    k_gru<<<dim3(E_LINKS / 64), b256, 0, stream>>>(aggb, h_bf, h_f32, kT, rkT, bi, br);
  }

  // readout
  k_seg<<<dim3(GG / 4), b256, 0, stream>>>(h_f32, goffs, gsum);
  k_mlp<<<dim3(GG), b256, 0, stream>>>(gsum, W1, b1, W2, b2, W3, b3, out);
}

// Round 2
// 1902.834 us; speedup vs baseline: 1.1681x; 1.1681x over previous
//
#include <hip/hip_runtime.h>
#include <hip/hip_bf16.h>

// Problem constants (match reference)
#define E_LINKS 131072
#define M_PAIRS 1048576
#define DDIM    64
#define GG      1024
#define RUNITS  256
#define TITER   8

typedef __attribute__((ext_vector_type(8))) short bf16x8;
typedef __attribute__((ext_vector_type(4))) float f32x4;

__device__ inline unsigned short f2bf(float f){
  union { float f; unsigned int u; } v; v.f = f;
  unsigned int u = v.u;
  unsigned int r = (u + 0x7FFFu + ((u >> 16) & 1u)) >> 16;
  return (unsigned short)r;
}
__device__ inline float bf2f(unsigned short u){
  union { unsigned int u; float f; } v; v.u = ((unsigned int)u) << 16; return v.f;
}
__device__ inline float selu_f(float x){
  // lambda = 1.0507009873554805, lambda*alpha = 1.7580993408473766
  return x > 0.f ? 1.0507009873554805f * x
                 : 1.7580993408473766f * (__expf(x) - 1.f);
}
__device__ inline float sigmoid_f(float x){ return 1.f / (1.f + __expf(-x)); }
__device__ inline float tanh_f(float x){
  float xc = fminf(fmaxf(x, -15.f), 15.f);
  float e2 = __expf(2.f * xc);
  return (e2 - 1.f) / (e2 + 1.f);
}

// ---------------- preprocessing ----------------

__global__ void k_zero(int* __restrict__ counts){
  int i = blockIdx.x * blockDim.x + threadIdx.x;
  if (i < E_LINKS) counts[i] = 0;
}

__global__ void k_hist(const int* __restrict__ second, int* __restrict__ counts){
  int i = blockIdx.x * blockDim.x + threadIdx.x;
  if (i < M_PAIRS) atomicAdd(&counts[second[i]], 1);
}

// 3-phase parallel exclusive scan over E_LINKS counts.
// Phase A: 512 blocks x 256 threads, block-reduce -> partials[512]
__global__ __launch_bounds__(256) void k_scan_reduce(const int* __restrict__ counts,
    int* __restrict__ partials){
  __shared__ int s[256];
  int t = threadIdx.x;
  int i = blockIdx.x * 256 + t;
  s[t] = counts[i];
  __syncthreads();
  #pragma unroll
  for (int off = 128; off > 0; off >>= 1){
    if (t < off) s[t] += s[t + off];
    __syncthreads();
  }
  if (t == 0) partials[blockIdx.x] = s[0];
}

// Phase B: single block of 512 threads scans partials in place (exclusive)
__global__ __launch_bounds__(512) void k_scan_part(int* __restrict__ partials){
  __shared__ int s[512];
  int t = threadIdx.x;
  int v = partials[t];
  s[t] = v;
  __syncthreads();
  for (int off = 1; off < 512; off <<= 1){
    int u = (t >= off) ? s[t - off] : 0;
    __syncthreads();
    s[t] += u;
    __syncthreads();
  }
  partials[t] = s[t] - v;
}

// Phase C: 512 blocks x 256 threads, per-block exclusive scan + partial offset
__global__ __launch_bounds__(256) void k_scan_apply(const int* __restrict__ counts,
    const int* __restrict__ partials, int* __restrict__ offsets,
    int* __restrict__ cursor){
  __shared__ int s[256];
  int t = threadIdx.x;
  int i = blockIdx.x * 256 + t;
  int c = counts[i];
  s[t] = c;
  __syncthreads();
  for (int off = 1; off < 256; off <<= 1){
    int u = (t >= off) ? s[t - off] : 0;
    __syncthreads();
    s[t] += u;
    __syncthreads();
  }
  int run = partials[blockIdx.x] + s[t] - c; // exclusive prefix
  offsets[i] = run;
  cursor[i] = run;
  if (i == E_LINKS - 1) offsets[E_LINKS] = run + c;
}

// graph_ids are SORTED: find segment boundaries directly.
__global__ void k_goffs(const int* __restrict__ gid, int* __restrict__ goffs){
  int i = blockIdx.x * blockDim.x + threadIdx.x;
  if (i >= E_LINKS) return;
  int g = gid[i];
  int gp = (i == 0) ? -1 : gid[i - 1];
  for (int x = gp + 1; x <= g; x++) goffs[x] = i;
  if (i == E_LINKS - 1){
    for (int x = g + 1; x <= GG; x++) goffs[x] = E_LINKS;
  }
}

__global__ void k_scatter(const int* __restrict__ first, const int* __restrict__ second,
    int* __restrict__ cursor, int* __restrict__ srcs){
  int i = blockIdx.x * blockDim.x + threadIdx.x;
  if (i < M_PAIRS){
    int e = second[i];
    int slot = atomicAdd(&cursor[e], 1);
    srcs[slot] = first[i];
  }
}

// Build transposed bf16 weights:
// WcT[c][k], c in [0,128): c<64 -> W_msg[k][c]; c>=64 -> W_msg[64+k][c-64]
// kT[c][k] = gru_kernel[k][c], rkT[c][k] = gru_rkernel[k][c]   (c in [0,192))
__global__ void k_prepw(const float* __restrict__ W_msg, const float* __restrict__ gk,
    const float* __restrict__ grk, unsigned short* __restrict__ WcT,
    unsigned short* __restrict__ kT, unsigned short* __restrict__ rkT){
  int i = blockIdx.x * blockDim.x + threadIdx.x;
  const int N1 = 128 * 64, N2 = 192 * 64;
  if (i < N1){
    int c = i >> 6, k = i & 63;
    float v = (c < 64) ? W_msg[k * 64 + c] : W_msg[(64 + k) * 64 + (c - 64)];
    WcT[i] = f2bf(v);
  } else if (i < N1 + N2){
    int j = i - N1; int c = j >> 6, k = j & 63;
    kT[j] = f2bf(gk[k * 192 + c]);
  } else if (i < N1 + 2 * N2){
    int j = i - N1 - N2; int c = j >> 6, k = j & 63;
    rkT[j] = f2bf(grk[k * 192 + c]);
  }
}

__global__ void k_init(const float* __restrict__ sa, float* __restrict__ hf,
                       unsigned short* __restrict__ hb){
  int i = blockIdx.x * blockDim.x + threadIdx.x; // E*64 threads
  float v = sa[i];
  hf[i] = v;
  hb[i] = f2bf(v);
}

// ---------------- main loop kernels ----------------

// AB[E,128] = h[E,64] @ Wc[64,128]  (+ b_msg on cols>=64), bf16 in/out, fp32 acc
__global__ __launch_bounds__(256) void k_ab(const unsigned short* __restrict__ hb,
    const unsigned short* __restrict__ WcT, const float* __restrict__ b_msg,
    unsigned short* __restrict__ AB){
  int wave = threadIdx.x >> 6, lane = threadIdx.x & 63;
  int row0 = (blockIdx.x * 4 + wave) * 16;
  int lr = lane & 15, lg = lane >> 4;
  f32x4 acc[8];
  #pragma unroll
  for (int i = 0; i < 8; i++) acc[i] = (f32x4){0.f, 0.f, 0.f, 0.f};
  #pragma unroll
  for (int s = 0; s < 2; s++){
    int kb = s * 32 + lg * 8;
    bf16x8 a = *(const bf16x8*)(hb + (size_t)(row0 + lr) * 64 + kb);
    #pragma unroll
    for (int ct = 0; ct < 8; ct++){
      bf16x8 b = *(const bf16x8*)(WcT + (ct * 16 + lr) * 64 + kb);
      acc[ct] = __builtin_amdgcn_mfma_f32_16x16x32_bf16(a, b, acc[ct], 0, 0, 0);
    }
  }
  #pragma unroll
  for (int ct = 0; ct < 8; ct++){
    int col = ct * 16 + lr;
    float bias = (col >= 64) ? b_msg[col - 64] : 0.f;
    #pragma unroll
    for (int q = 0; q < 4; q++){
      int row = row0 + lg * 4 + q;
      AB[(size_t)row * 128 + col] = f2bf(acc[ct][q] + bias);
    }
  }
}

// agg[e][:] = sum over incoming msgs: selu(A[src] + B[e])
__global__ __launch_bounds__(256) void k_agg(const unsigned short* __restrict__ AB,
    const int* __restrict__ offsets, const int* __restrict__ srcs,
    unsigned short* __restrict__ agg){
  int wave = threadIdx.x >> 6, lane = threadIdx.x & 63;
  int e = blockIdx.x * 4 + wave;
  float bv = bf2f(AB[(size_t)e * 128 + 64 + lane]);
  int beg = offsets[e], end = offsets[e + 1];
  float acc = 0.f;
  for (int i = beg; i < end; i++){
    int s = srcs[i];
    acc += selu_f(bf2f(AB[(size_t)s * 128 + lane]) + bv);
  }
  agg[(size_t)e * 64 + lane] = f2bf(acc);
}

// Fused GRU: mx = agg@k + bi, mh = h@rk + br, gates, in-place h update
__global__ __launch_bounds__(256) void k_gru(const unsigned short* __restrict__ agg,
    unsigned short* __restrict__ hb, float* __restrict__ hf,
    const unsigned short* __restrict__ kT, const unsigned short* __restrict__ rkT,
    const float* __restrict__ bi, const float* __restrict__ br){
  int wave = threadIdx.x >> 6, lane = threadIdx.x & 63;
  int row0 = (blockIdx.x * 4 + wave) * 16;
  int lr = lane & 15, lg = lane >> 4;
  f32x4 ax[12], ah[12];
  #pragma unroll
  for (int i = 0; i < 12; i++){ ax[i] = (f32x4){0.f,0.f,0.f,0.f}; ah[i] = (f32x4){0.f,0.f,0.f,0.f}; }
  #pragma unroll
  for (int s = 0; s < 2; s++){
    int kb = s * 32 + lg * 8;
    bf16x8 xa = *(const bf16x8*)(agg + (size_t)(row0 + lr) * 64 + kb);
    bf16x8 ha = *(const bf16x8*)(hb  + (size_t)(row0 + lr) * 64 + kb);
    #pragma unroll
    for (int ct = 0; ct < 12; ct++){
      bf16x8 bx = *(const bf16x8*)(kT + (ct * 16 + lr) * 64 + kb);
      ax[ct] = __builtin_amdgcn_mfma_f32_16x16x32_bf16(xa, bx, ax[ct], 0, 0, 0);
    }
    #pragma unroll
    for (int ct = 0; ct < 12; ct++){
      bf16x8 bh = *(const bf16x8*)(rkT + (ct * 16 + lr) * 64 + kb);
      ah[ct] = __builtin_amdgcn_mfma_f32_16x16x32_bf16(ha, bh, ah[ct], 0, 0, 0);
    }
  }
  #pragma unroll
  for (int jt = 0; jt < 4; jt++){
    int j = jt * 16 + lr;
    float biz = bi[j], bir = bi[64 + j], bih = bi[128 + j];
    float brz = br[j], brr = br[64 + j], brh = br[128 + j];
    #pragma unroll
    for (int q = 0; q < 4; q++){
      int row = row0 + lg * 4 + q;
      float xz = ax[jt][q] + biz,     hz = ah[jt][q] + brz;
      float xr = ax[4 + jt][q] + bir, hr = ah[4 + jt][q] + brr;
      float xh = ax[8 + jt][q] + bih, hh = ah[8 + jt][q] + brh;
      float z = sigmoid_f(xz + hz);
      float r = sigmoid_f(xr + hr);
      float c = tanh_f(xh + r * hh);
      size_t idx = (size_t)row * 64 + j;
      float hold = hf[idx];
      float hn = z * hold + (1.f - z) * c;
      hf[idx] = hn;
      hb[idx] = f2bf(hn);
    }
  }
}

// ---------------- readout ----------------

__global__ __launch_bounds__(256) void k_seg(const float* __restrict__ hf,
    const int* __restrict__ goff, float* __restrict__ gsum){
  int wave = threadIdx.x >> 6, lane = threadIdx.x & 63;
  int g = blockIdx.x * 4 + wave;
  int beg = goff[g], end = goff[g + 1];
  float acc = 0.f;
  for (int e = beg; e < end; e++) acc += hf[(size_t)e * 64 + lane];
  gsum[(size_t)g * 64 + lane] = acc;
}

__global__ __launch_bounds__(256) void k_mlp(const float* __restrict__ gsum,
    const float* __restrict__ W1, const float* __restrict__ b1,
    const float* __restrict__ W2, const float* __restrict__ b2,
    const float* __restrict__ W3, const float* __restrict__ b3,
    float* __restrict__ out){
  __shared__ float sg[64];
  __shared__ float sr1[256];
  __shared__ float sr2[256];
  __shared__ float wsum[4];
  int g = blockIdx.x, t = threadIdx.x;
  if (t < 64) sg[t] = gsum[(size_t)g * 64 + t];
  __syncthreads();
  float a = b1[t];
  #pragma unroll
  for (int k = 0; k < 64; k++) a += sg[k] * W1[k * 256 + t];
  sr1[t] = selu_f(a);
  __syncthreads();
  float b = b2[t];
  for (int k = 0; k < 256; k++) b += sr1[k] * W2[k * 256 + t];
  sr2[t] = selu_f(b);
  __syncthreads();
  float v = sr2[t] * W3[t];
  for (int off = 32; off > 0; off >>= 1) v += __shfl_down(v, off, 64);
  if ((t & 63) == 0) wsum[t >> 6] = v;
  __syncthreads();
  if (t == 0) out[g] = wsum[0] + wsum[1] + wsum[2] + wsum[3] + b3[0];
}

// ---------------- host ----------------

static inline size_t alignup(size_t x){ return (x + 255) & ~(size_t)255; }

extern "C" void kernel_launch(void* const* d_in, const int* in_sizes, int n_in,
                              void* d_out, int out_size, void* d_ws, size_t ws_size,
                              hipStream_t stream) {
  const float* states_action = (const float*)d_in[0];
  const int*   graph_ids     = (const int*)d_in[1];
  const int*   first         = (const int*)d_in[2];
  const int*   second        = (const int*)d_in[3];
  const float* W_msg         = (const float*)d_in[5];
  const float* b_msg         = (const float*)d_in[6];
  const float* gk            = (const float*)d_in[7];
  const float* grk           = (const float*)d_in[8];
  const float* bi            = (const float*)d_in[9];
  const float* br            = (const float*)d_in[10];
  const float* W1            = (const float*)d_in[11];
  const float* b1            = (const float*)d_in[12];
  const float* W2            = (const float*)d_in[13];
  const float* b2            = (const float*)d_in[14];
  const float* W3            = (const float*)d_in[15];
  const float* b3            = (const float*)d_in[16];
  float* out = (float*)d_out;

  char* ws = (char*)d_ws;
  size_t off = 0;
  float*          h_f32  = (float*)(ws + off);          off += alignup((size_t)E_LINKS * 64 * 4);
  unsigned short* h_bf   = (unsigned short*)(ws + off); off += alignup((size_t)E_LINKS * 64 * 2);
  unsigned short* aggb   = (unsigned short*)(ws + off); off += alignup((size_t)E_LINKS * 64 * 2);
  unsigned short* AB     = (unsigned short*)(ws + off); off += alignup((size_t)E_LINKS * 128 * 2);
  unsigned short* WcT    = (unsigned short*)(ws + off); off += alignup(128 * 64 * 2);
  unsigned short* kT     = (unsigned short*)(ws + off); off += alignup(192 * 64 * 2);
  unsigned short* rkT    = (unsigned short*)(ws + off); off += alignup(192 * 64 * 2);
  int*            counts = (int*)(ws + off);            off += alignup((size_t)E_LINKS * 4);
  int*            offs   = (int*)(ws + off);            off += alignup(((size_t)E_LINKS + 1) * 4);
  int*            cursor = (int*)(ws + off);            off += alignup((size_t)E_LINKS * 4);
  int*            srcs   = (int*)(ws + off);            off += alignup((size_t)M_PAIRS * 4);
  int*            parts  = (int*)(ws + off);            off += alignup(512 * 4);
  int*            goffs  = (int*)(ws + off);            off += alignup(((size_t)GG + 1) * 4);
  float*          gsum   = (float*)(ws + off);          off += alignup((size_t)GG * 64 * 4);

  dim3 b256(256);

  // CSR preprocessing (3-phase scan; graph offsets via sorted-boundary scan)
  k_zero<<<dim3(E_LINKS / 256), b256, 0, stream>>>(counts);
  k_hist<<<dim3(M_PAIRS / 256), b256, 0, stream>>>(second, counts);
  k_scan_reduce<<<dim3(512), b256, 0, stream>>>(counts, parts);
  k_scan_part<<<dim3(1), dim3(512), 0, stream>>>(parts);
  k_scan_apply<<<dim3(512), b256, 0, stream>>>(counts, parts, offs, cursor);
  k_goffs<<<dim3(E_LINKS / 256), b256, 0, stream>>>(graph_ids, goffs);
  k_scatter<<<dim3(M_PAIRS / 256), b256, 0, stream>>>(first, second, cursor, srcs);

  // weights + h init
  k_prepw<<<dim3(128), b256, 0, stream>>>(W_msg, gk, grk, WcT, kT, rkT);
  k_init<<<dim3(E_LINKS * 64 / 256), b256, 0, stream>>>(states_action, h_f32, h_bf);

  // message passing
  for (int t = 0; t < TITER; t++){
    k_ab <<<dim3(E_LINKS / 64), b256, 0, stream>>>(h_bf, WcT, b_msg, AB);
    k_agg<<<dim3(E_LINKS / 4),  b256, 0, stream>>>(AB, offs, srcs, aggb);
    k_gru<<<dim3(E_LINKS / 64), b256, 0, stream>>>(aggb, h_bf, h_f32, kT, rkT, bi, br);
  }

  // readout
  k_seg<<<dim3(GG / 4), b256, 0, stream>>>(h_f32, goffs, gsum);
  k_mlp<<<dim3(GG), b256, 0, stream>>>(gsum, W1, b1, W2, b2, W3, b3, out);
}

// Round 3
// 1364.801 us; speedup vs baseline: 1.6286x; 1.3942x over previous
//
#include <hip/hip_runtime.h>
#include <hip/hip_bf16.h>

// Problem constants (match reference)
#define E_LINKS 131072
#define M_PAIRS 1048576
#define DDIM    64
#define GG      1024
#define RUNITS  256
#define TITER   8

typedef __attribute__((ext_vector_type(8))) short bf16x8;
typedef __attribute__((ext_vector_type(4))) float f32x4;

__device__ inline unsigned short f2bf(float f){
  union { float f; unsigned int u; } v; v.f = f;
  unsigned int u = v.u;
  unsigned int r = (u + 0x7FFFu + ((u >> 16) & 1u)) >> 16;
  return (unsigned short)r;
}
__device__ inline float bf2f(unsigned short u){
  union { unsigned int u; float f; } v; v.u = ((unsigned int)u) << 16; return v.f;
}
__device__ inline float selu_f(float x){
  // lambda = 1.0507009873554805, lambda*alpha = 1.7580993408473766
  return x > 0.f ? 1.0507009873554805f * x
                 : 1.7580993408473766f * (__expf(x) - 1.f);
}
__device__ inline float sigmoid_f(float x){ return 1.f / (1.f + __expf(-x)); }
__device__ inline float tanh_f(float x){
  float xc = fminf(fmaxf(x, -15.f), 15.f);
  float e2 = __expf(2.f * xc);
  return (e2 - 1.f) / (e2 + 1.f);
}

// ---------------- preprocessing ----------------

__global__ void k_zero(int* __restrict__ counts){
  int i = blockIdx.x * blockDim.x + threadIdx.x;
  if (i < E_LINKS) counts[i] = 0;
}

__global__ void k_hist(const int* __restrict__ second, int* __restrict__ counts){
  int i = blockIdx.x * blockDim.x + threadIdx.x;
  if (i < M_PAIRS) atomicAdd(&counts[second[i]], 1);
}

// 3-phase parallel exclusive scan over E_LINKS counts.
__global__ __launch_bounds__(256) void k_scan_reduce(const int* __restrict__ counts,
    int* __restrict__ partials){
  __shared__ int s[256];
  int t = threadIdx.x;
  int i = blockIdx.x * 256 + t;
  s[t] = counts[i];
  __syncthreads();
  #pragma unroll
  for (int off = 128; off > 0; off >>= 1){
    if (t < off) s[t] += s[t + off];
    __syncthreads();
  }
  if (t == 0) partials[blockIdx.x] = s[0];
}

__global__ __launch_bounds__(512) void k_scan_part(int* __restrict__ partials){
  __shared__ int s[512];
  int t = threadIdx.x;
  int v = partials[t];
  s[t] = v;
  __syncthreads();
  for (int off = 1; off < 512; off <<= 1){
    int u = (t >= off) ? s[t - off] : 0;
    __syncthreads();
    s[t] += u;
    __syncthreads();
  }
  partials[t] = s[t] - v;
}

__global__ __launch_bounds__(256) void k_scan_apply(const int* __restrict__ counts,
    const int* __restrict__ partials, int* __restrict__ offsets,
    int* __restrict__ cursor){
  __shared__ int s[256];
  int t = threadIdx.x;
  int i = blockIdx.x * 256 + t;
  int c = counts[i];
  s[t] = c;
  __syncthreads();
  for (int off = 1; off < 256; off <<= 1){
    int u = (t >= off) ? s[t - off] : 0;
    __syncthreads();
    s[t] += u;
    __syncthreads();
  }
  int run = partials[blockIdx.x] + s[t] - c; // exclusive prefix
  offsets[i] = run;
  cursor[i] = run;
  if (i == E_LINKS - 1) offsets[E_LINKS] = run + c;
}

// graph_ids are SORTED: find segment boundaries directly.
__global__ void k_goffs(const int* __restrict__ gid, int* __restrict__ goffs){
  int i = blockIdx.x * blockDim.x + threadIdx.x;
  if (i >= E_LINKS) return;
  int g = gid[i];
  int gp = (i == 0) ? -1 : gid[i - 1];
  for (int x = gp + 1; x <= g; x++) goffs[x] = i;
  if (i == E_LINKS - 1){
    for (int x = g + 1; x <= GG; x++) goffs[x] = E_LINKS;
  }
}

__global__ void k_scatter(const int* __restrict__ first, const int* __restrict__ second,
    int* __restrict__ cursor, int* __restrict__ srcs){
  int i = blockIdx.x * blockDim.x + threadIdx.x;
  if (i < M_PAIRS){
    int e = second[i];
    int slot = atomicAdd(&cursor[e], 1);
    srcs[slot] = first[i];
  }
}

// Build transposed bf16 weights.
__global__ void k_prepw(const float* __restrict__ W_msg, const float* __restrict__ gk,
    const float* __restrict__ grk, unsigned short* __restrict__ WcT,
    unsigned short* __restrict__ kT, unsigned short* __restrict__ rkT){
  int i = blockIdx.x * blockDim.x + threadIdx.x;
  const int N1 = 128 * 64, N2 = 192 * 64;
  if (i < N1){
    int c = i >> 6, k = i & 63;
    float v = (c < 64) ? W_msg[k * 64 + c] : W_msg[(64 + k) * 64 + (c - 64)];
    WcT[i] = f2bf(v);
  } else if (i < N1 + N2){
    int j = i - N1; int c = j >> 6, k = j & 63;
    kT[j] = f2bf(gk[k * 192 + c]);
  } else if (i < N1 + 2 * N2){
    int j = i - N1 - N2; int c = j >> 6, k = j & 63;
    rkT[j] = f2bf(grk[k * 192 + c]);
  }
}

__global__ void k_init(const float* __restrict__ sa, float* __restrict__ hf,
                       unsigned short* __restrict__ hb){
  int i = blockIdx.x * blockDim.x + threadIdx.x; // E*64 threads
  float v = sa[i];
  hf[i] = v;
  hb[i] = f2bf(v);
}

// ---------------- main loop kernels ----------------

// AB[E,128] = h[E,64] @ Wc[64,128]  (+ b_msg on cols>=64), bf16 in/out, fp32 acc
__global__ __launch_bounds__(256) void k_ab(const unsigned short* __restrict__ hb,
    const unsigned short* __restrict__ WcT, const float* __restrict__ b_msg,
    unsigned short* __restrict__ AB){
  int wave = threadIdx.x >> 6, lane = threadIdx.x & 63;
  int row0 = (blockIdx.x * 4 + wave) * 16;
  int lr = lane & 15, lg = lane >> 4;
  f32x4 acc[8];
  #pragma unroll
  for (int i = 0; i < 8; i++) acc[i] = (f32x4){0.f, 0.f, 0.f, 0.f};
  #pragma unroll
  for (int s = 0; s < 2; s++){
    int kb = s * 32 + lg * 8;
    bf16x8 a = *(const bf16x8*)(hb + (size_t)(row0 + lr) * 64 + kb);
    #pragma unroll
    for (int ct = 0; ct < 8; ct++){
      bf16x8 b = *(const bf16x8*)(WcT + (ct * 16 + lr) * 64 + kb);
      acc[ct] = __builtin_amdgcn_mfma_f32_16x16x32_bf16(a, b, acc[ct], 0, 0, 0);
    }
  }
  #pragma unroll
  for (int ct = 0; ct < 8; ct++){
    int col = ct * 16 + lr;
    float bias = (col >= 64) ? b_msg[col - 64] : 0.f;
    #pragma unroll
    for (int q = 0; q < 4; q++){
      int row = row0 + lg * 4 + q;
      AB[(size_t)row * 128 + col] = f2bf(acc[ct][q] + bias);
    }
  }
}

// agg[e][:] = sum over incoming msgs: selu(A[src] + B[e])
// One wave per edge; 4 lane-groups of 16 each gather one 128B source row
// per iteration (ushort4/lane), 2x unrolled -> 8 rows in flight.
__global__ __launch_bounds__(256) void k_agg(const unsigned short* __restrict__ AB,
    const int* __restrict__ offsets, const int* __restrict__ srcs,
    unsigned short* __restrict__ agg){
  int wave = threadIdx.x >> 6, lane = threadIdx.x & 63;
  int e = blockIdx.x * 4 + wave;
  int g = lane >> 4, d = lane & 15;

  const ushort4* Bq = (const ushort4*)(AB + (size_t)e * 128 + 64 + d * 4);
  ushort4 bq = *Bq;
  float b0 = bf2f(bq.x), b1 = bf2f(bq.y), b2 = bf2f(bq.z), b3 = bf2f(bq.w);

  int beg = offsets[e], end = offsets[e + 1];
  float a0 = 0.f, a1 = 0.f, a2 = 0.f, a3 = 0.f;

  int i = beg + g;
  // 2x unrolled: 8 source rows in flight per wave
  for (; i + 4 < end; i += 8){
    int s0 = srcs[i];
    int s1 = srcs[i + 4];
    ushort4 q0 = *(const ushort4*)(AB + (size_t)s0 * 128 + d * 4);
    ushort4 q1 = *(const ushort4*)(AB + (size_t)s1 * 128 + d * 4);
    a0 += selu_f(bf2f(q0.x) + b0);
    a1 += selu_f(bf2f(q0.y) + b1);
    a2 += selu_f(bf2f(q0.z) + b2);
    a3 += selu_f(bf2f(q0.w) + b3);
    a0 += selu_f(bf2f(q1.x) + b0);
    a1 += selu_f(bf2f(q1.y) + b1);
    a2 += selu_f(bf2f(q1.z) + b2);
    a3 += selu_f(bf2f(q1.w) + b3);
  }
  if (i < end){
    int s0 = srcs[i];
    ushort4 q0 = *(const ushort4*)(AB + (size_t)s0 * 128 + d * 4);
    a0 += selu_f(bf2f(q0.x) + b0);
    a1 += selu_f(bf2f(q0.y) + b1);
    a2 += selu_f(bf2f(q0.z) + b2);
    a3 += selu_f(bf2f(q0.w) + b3);
  }

  // reduce across the 4 lane groups (same dims, different sources)
  a0 += __shfl_xor(a0, 16, 64); a0 += __shfl_xor(a0, 32, 64);
  a1 += __shfl_xor(a1, 16, 64); a1 += __shfl_xor(a1, 32, 64);
  a2 += __shfl_xor(a2, 16, 64); a2 += __shfl_xor(a2, 32, 64);
  a3 += __shfl_xor(a3, 16, 64); a3 += __shfl_xor(a3, 32, 64);

  if (g == 0){
    ushort4 o;
    o.x = f2bf(a0); o.y = f2bf(a1); o.z = f2bf(a2); o.w = f2bf(a3);
    *(ushort4*)(agg + (size_t)e * 64 + d * 4) = o;
  }
}

// Fused GRU: mx = agg@k + bi, mh = h@rk + br, gates, in-place h update
__global__ __launch_bounds__(256) void k_gru(const unsigned short* __restrict__ agg,
    unsigned short* __restrict__ hb, float* __restrict__ hf,
    const unsigned short* __restrict__ kT, const unsigned short* __restrict__ rkT,
    const float* __restrict__ bi, const float* __restrict__ br){
  int wave = threadIdx.x >> 6, lane = threadIdx.x & 63;
  int row0 = (blockIdx.x * 4 + wave) * 16;
  int lr = lane & 15, lg = lane >> 4;
  f32x4 ax[12], ah[12];
  #pragma unroll
  for (int i = 0; i < 12; i++){ ax[i] = (f32x4){0.f,0.f,0.f,0.f}; ah[i] = (f32x4){0.f,0.f,0.f,0.f}; }
  #pragma unroll
  for (int s = 0; s < 2; s++){
    int kb = s * 32 + lg * 8;
    bf16x8 xa = *(const bf16x8*)(agg + (size_t)(row0 + lr) * 64 + kb);
    bf16x8 ha = *(const bf16x8*)(hb  + (size_t)(row0 + lr) * 64 + kb);
    #pragma unroll
    for (int ct = 0; ct < 12; ct++){
      bf16x8 bx = *(const bf16x8*)(kT + (ct * 16 + lr) * 64 + kb);
      ax[ct] = __builtin_amdgcn_mfma_f32_16x16x32_bf16(xa, bx, ax[ct], 0, 0, 0);
    }
    #pragma unroll
    for (int ct = 0; ct < 12; ct++){
      bf16x8 bh = *(const bf16x8*)(rkT + (ct * 16 + lr) * 64 + kb);
      ah[ct] = __builtin_amdgcn_mfma_f32_16x16x32_bf16(ha, bh, ah[ct], 0, 0, 0);
    }
  }
  #pragma unroll
  for (int jt = 0; jt < 4; jt++){
    int j = jt * 16 + lr;
    float biz = bi[j], bir = bi[64 + j], bih = bi[128 + j];
    float brz = br[j], brr = br[64 + j], brh = br[128 + j];
    #pragma unroll
    for (int q = 0; q < 4; q++){
      int row = row0 + lg * 4 + q;
      float xz = ax[jt][q] + biz,     hz = ah[jt][q] + brz;
      float xr = ax[4 + jt][q] + bir, hr = ah[4 + jt][q] + brr;
      float xh = ax[8 + jt][q] + bih, hh = ah[8 + jt][q] + brh;
      float z = sigmoid_f(xz + hz);
      float r = sigmoid_f(xr + hr);
      float c = tanh_f(xh + r * hh);
      size_t idx = (size_t)row * 64 + j;
      float hold = hf[idx];
      float hn = z * hold + (1.f - z) * c;
      hf[idx] = hn;
      hb[idx] = f2bf(hn);
    }
  }
}

// ---------------- readout ----------------

__global__ __launch_bounds__(256) void k_seg(const float* __restrict__ hf,
    const int* __restrict__ goff, float* __restrict__ gsum){
  int wave = threadIdx.x >> 6, lane = threadIdx.x & 63;
  int g = blockIdx.x * 4 + wave;
  int beg = goff[g], end = goff[g + 1];
  float acc = 0.f;
  for (int e = beg; e < end; e++) acc += hf[(size_t)e * 64 + lane];
  gsum[(size_t)g * 64 + lane] = acc;
}

__global__ __launch_bounds__(256) void k_mlp(const float* __restrict__ gsum,
    const float* __restrict__ W1, const float* __restrict__ b1,
    const float* __restrict__ W2, const float* __restrict__ b2,
    const float* __restrict__ W3, const float* __restrict__ b3,
    float* __restrict__ out){
  __shared__ float sg[64];
  __shared__ float sr1[256];
  __shared__ float sr2[256];
  __shared__ float wsum[4];
  int g = blockIdx.x, t = threadIdx.x;
  if (t < 64) sg[t] = gsum[(size_t)g * 64 + t];
  __syncthreads();
  float a = b1[t];
  #pragma unroll
  for (int k = 0; k < 64; k++) a += sg[k] * W1[k * 256 + t];
  sr1[t] = selu_f(a);
  __syncthreads();
  float b = b2[t];
  for (int k = 0; k < 256; k++) b += sr1[k] * W2[k * 256 + t];
  sr2[t] = selu_f(b);
  __syncthreads();
  float v = sr2[t] * W3[t];
  for (int off = 32; off > 0; off >>= 1) v += __shfl_down(v, off, 64);
  if ((t & 63) == 0) wsum[t >> 6] = v;
  __syncthreads();
  if (t == 0) out[g] = wsum[0] + wsum[1] + wsum[2] + wsum[3] + b3[0];
}

// ---------------- host ----------------

static inline size_t alignup(size_t x){ return (x + 255) & ~(size_t)255; }

extern "C" void kernel_launch(void* const* d_in, const int* in_sizes, int n_in,
                              void* d_out, int out_size, void* d_ws, size_t ws_size,
                              hipStream_t stream) {
  const float* states_action = (const float*)d_in[0];
  const int*   graph_ids     = (const int*)d_in[1];
  const int*   first         = (const int*)d_in[2];
  const int*   second        = (const int*)d_in[3];
  const float* W_msg         = (const float*)d_in[5];
  const float* b_msg         = (const float*)d_in[6];
  const float* gk            = (const float*)d_in[7];
  const float* grk           = (const float*)d_in[8];
  const float* bi            = (const float*)d_in[9];
  const float* br            = (const float*)d_in[10];
  const float* W1            = (const float*)d_in[11];
  const float* b1            = (const float*)d_in[12];
  const float* W2            = (const float*)d_in[13];
  const float* b2            = (const float*)d_in[14];
  const float* W3            = (const float*)d_in[15];
  const float* b3            = (const float*)d_in[16];
  float* out = (float*)d_out;

  char* ws = (char*)d_ws;
  size_t off = 0;
  float*          h_f32  = (float*)(ws + off);          off += alignup((size_t)E_LINKS * 64 * 4);
  unsigned short* h_bf   = (unsigned short*)(ws + off); off += alignup((size_t)E_LINKS * 64 * 2);
  unsigned short* aggb   = (unsigned short*)(ws + off); off += alignup((size_t)E_LINKS * 64 * 2);
  unsigned short* AB     = (unsigned short*)(ws + off); off += alignup((size_t)E_LINKS * 128 * 2);
  unsigned short* WcT    = (unsigned short*)(ws + off); off += alignup(128 * 64 * 2);
  unsigned short* kT     = (unsigned short*)(ws + off); off += alignup(192 * 64 * 2);
  unsigned short* rkT    = (unsigned short*)(ws + off); off += alignup(192 * 64 * 2);
  int*            counts = (int*)(ws + off);            off += alignup((size_t)E_LINKS * 4);
  int*            offs   = (int*)(ws + off);            off += alignup(((size_t)E_LINKS + 1) * 4);
  int*            cursor = (int*)(ws + off);            off += alignup((size_t)E_LINKS * 4);
  int*            srcs   = (int*)(ws + off);            off += alignup((size_t)M_PAIRS * 4);
  int*            parts  = (int*)(ws + off);            off += alignup(512 * 4);
  int*            goffs  = (int*)(ws + off);            off += alignup(((size_t)GG + 1) * 4);
  float*          gsum   = (float*)(ws + off);          off += alignup((size_t)GG * 64 * 4);

  dim3 b256(256);

  // CSR preprocessing
  k_zero<<<dim3(E_LINKS / 256), b256, 0, stream>>>(counts);
  k_hist<<<dim3(M_PAIRS / 256), b256, 0, stream>>>(second, counts);
  k_scan_reduce<<<dim3(512), b256, 0, stream>>>(counts, parts);
  k_scan_part<<<dim3(1), dim3(512), 0, stream>>>(parts);
  k_scan_apply<<<dim3(512), b256, 0, stream>>>(counts, parts, offs, cursor);
  k_goffs<<<dim3(E_LINKS / 256), b256, 0, stream>>>(graph_ids, goffs);
  k_scatter<<<dim3(M_PAIRS / 256), b256, 0, stream>>>(first, second, cursor, srcs);

  // weights + h init
  k_prepw<<<dim3(128), b256, 0, stream>>>(W_msg, gk, grk, WcT, kT, rkT);
  k_init<<<dim3(E_LINKS * 64 / 256), b256, 0, stream>>>(states_action, h_f32, h_bf);

  // message passing
  for (int t = 0; t < TITER; t++){
    k_ab <<<dim3(E_LINKS / 64), b256, 0, stream>>>(h_bf, WcT, b_msg, AB);
    k_agg<<<dim3(E_LINKS / 4),  b256, 0, stream>>>(AB, offs, srcs, aggb);
    k_gru<<<dim3(E_LINKS / 64), b256, 0, stream>>>(aggb, h_bf, h_f32, kT, rkT, bi, br);
  }

  // readout
  k_seg<<<dim3(GG / 4), b256, 0, stream>>>(h_f32, goffs, gsum);
  k_mlp<<<dim3(GG), b256, 0, stream>>>(gsum, W1, b1, W2, b2, W3, b3, out);
}

// Round 4
// 1189.427 us; speedup vs baseline: 1.8687x; 1.1474x over previous
//
#include <hip/hip_runtime.h>
#include <hip/hip_bf16.h>

// Problem constants (match reference)
#define E_LINKS 131072
#define M_PAIRS 1048576
#define DDIM    64
#define GG      1024
#define RUNITS  256
#define TITER   8

typedef __attribute__((ext_vector_type(8))) short bf16x8;
typedef __attribute__((ext_vector_type(4))) float f32x4;

__device__ inline unsigned short f2bf(float f){
  union { float f; unsigned int u; } v; v.f = f;
  unsigned int u = v.u;
  unsigned int r = (u + 0x7FFFu + ((u >> 16) & 1u)) >> 16;
  return (unsigned short)r;
}
__device__ inline float bf2f(unsigned short u){
  union { unsigned int u; float f; } v; v.u = ((unsigned int)u) << 16; return v.f;
}
__device__ inline float selu_f(float x){
  return x > 0.f ? 1.0507009873554805f * x
                 : 1.7580993408473766f * (__expf(x) - 1.f);
}
__device__ inline float sigmoid_f(float x){ return 1.f / (1.f + __expf(-x)); }
__device__ inline float tanh_f(float x){
  float xc = fminf(fmaxf(x, -15.f), 15.f);
  float e2 = __expf(2.f * xc);
  return (e2 - 1.f) / (e2 + 1.f);
}

// pack 8 contiguous f32 -> bf16x8 fragment
__device__ inline bf16x8 packbf8(const float* __restrict__ p){
  float4 u0 = *(const float4*)(p);
  float4 u1 = *(const float4*)(p + 4);
  bf16x8 r;
  r[0] = (short)f2bf(u0.x); r[1] = (short)f2bf(u0.y);
  r[2] = (short)f2bf(u0.z); r[3] = (short)f2bf(u0.w);
  r[4] = (short)f2bf(u1.x); r[5] = (short)f2bf(u1.y);
  r[6] = (short)f2bf(u1.z); r[7] = (short)f2bf(u1.w);
  return r;
}

// ---------------- preprocessing ----------------

__global__ void k_zero(int* __restrict__ counts){
  int i = blockIdx.x * blockDim.x + threadIdx.x;
  if (i < E_LINKS) counts[i] = 0;
}

__global__ void k_hist(const int* __restrict__ second, int* __restrict__ counts){
  int i = blockIdx.x * blockDim.x + threadIdx.x;
  if (i < M_PAIRS) atomicAdd(&counts[second[i]], 1);
}

__global__ __launch_bounds__(256) void k_scan_reduce(const int* __restrict__ counts,
    int* __restrict__ partials){
  __shared__ int s[256];
  int t = threadIdx.x;
  int i = blockIdx.x * 256 + t;
  s[t] = counts[i];
  __syncthreads();
  #pragma unroll
  for (int off = 128; off > 0; off >>= 1){
    if (t < off) s[t] += s[t + off];
    __syncthreads();
  }
  if (t == 0) partials[blockIdx.x] = s[0];
}

__global__ __launch_bounds__(512) void k_scan_part(int* __restrict__ partials){
  __shared__ int s[512];
  int t = threadIdx.x;
  int v = partials[t];
  s[t] = v;
  __syncthreads();
  for (int off = 1; off < 512; off <<= 1){
    int u = (t >= off) ? s[t - off] : 0;
    __syncthreads();
    s[t] += u;
    __syncthreads();
  }
  partials[t] = s[t] - v;
}

__global__ __launch_bounds__(256) void k_scan_apply(const int* __restrict__ counts,
    const int* __restrict__ partials, int* __restrict__ offsets,
    int* __restrict__ cursor){
  __shared__ int s[256];
  int t = threadIdx.x;
  int i = blockIdx.x * 256 + t;
  int c = counts[i];
  s[t] = c;
  __syncthreads();
  for (int off = 1; off < 256; off <<= 1){
    int u = (t >= off) ? s[t - off] : 0;
    __syncthreads();
    s[t] += u;
    __syncthreads();
  }
  int run = partials[blockIdx.x] + s[t] - c;
  offsets[i] = run;
  cursor[i] = run;
  if (i == E_LINKS - 1) offsets[E_LINKS] = run + c;
}

__global__ void k_goffs(const int* __restrict__ gid, int* __restrict__ goffs){
  int i = blockIdx.x * blockDim.x + threadIdx.x;
  if (i >= E_LINKS) return;
  int g = gid[i];
  int gp = (i == 0) ? -1 : gid[i - 1];
  for (int x = gp + 1; x <= g; x++) goffs[x] = i;
  if (i == E_LINKS - 1){
    for (int x = g + 1; x <= GG; x++) goffs[x] = E_LINKS;
  }
}

__global__ void k_scatter(const int* __restrict__ first, const int* __restrict__ second,
    int* __restrict__ cursor, int* __restrict__ srcs){
  int i = blockIdx.x * blockDim.x + threadIdx.x;
  if (i < M_PAIRS){
    int e = second[i];
    int slot = atomicAdd(&cursor[e], 1);
    srcs[slot] = first[i];
  }
}

// Build transposed bf16 weights.
__global__ void k_prepw(const float* __restrict__ W_msg, const float* __restrict__ gk,
    const float* __restrict__ grk, unsigned short* __restrict__ WcT,
    unsigned short* __restrict__ kT, unsigned short* __restrict__ rkT){
  int i = blockIdx.x * blockDim.x + threadIdx.x;
  const int N1 = 128 * 64, N2 = 192 * 64;
  if (i < N1){
    int c = i >> 6, k = i & 63;
    float v = (c < 64) ? W_msg[k * 64 + c] : W_msg[(64 + k) * 64 + (c - 64)];
    WcT[i] = f2bf(v);
  } else if (i < N1 + N2){
    int j = i - N1; int c = j >> 6, k = j & 63;
    kT[j] = f2bf(gk[k * 192 + c]);
  } else if (i < N1 + 2 * N2){
    int j = i - N1 - N2; int c = j >> 6, k = j & 63;
    rkT[j] = f2bf(grk[k * 192 + c]);
  }
}

// ---------------- main loop kernels ----------------

// AB[E,128] = h[E,64] @ Wc[64,128] (+ b_msg on cols>=64); h read as f32.
__global__ __launch_bounds__(256) void k_ab0(const float* __restrict__ hf,
    const unsigned short* __restrict__ WcT, const float* __restrict__ b_msg,
    unsigned short* __restrict__ AB){
  int wave = threadIdx.x >> 6, lane = threadIdx.x & 63;
  int row0 = (blockIdx.x * 4 + wave) * 16;
  int lr = lane & 15, lg = lane >> 4;
  f32x4 acc[8];
  #pragma unroll
  for (int i = 0; i < 8; i++) acc[i] = (f32x4){0.f, 0.f, 0.f, 0.f};
  #pragma unroll
  for (int s = 0; s < 2; s++){
    int kb = s * 32 + lg * 8;
    bf16x8 a = packbf8(hf + (size_t)(row0 + lr) * 64 + kb);
    #pragma unroll
    for (int ct = 0; ct < 8; ct++){
      bf16x8 b = *(const bf16x8*)(WcT + (ct * 16 + lr) * 64 + kb);
      acc[ct] = __builtin_amdgcn_mfma_f32_16x16x32_bf16(a, b, acc[ct], 0, 0, 0);
    }
  }
  #pragma unroll
  for (int ct = 0; ct < 8; ct++){
    int col = ct * 16 + lr;
    float bias = (col >= 64) ? b_msg[col - 64] : 0.f;
    #pragma unroll
    for (int q = 0; q < 4; q++){
      int row = row0 + lg * 4 + q;
      AB[(size_t)row * 128 + col] = f2bf(acc[ct][q] + bias);
    }
  }
}

// agg[e][:] = sum over incoming msgs: selu(A[src] + B[e])
__global__ __launch_bounds__(256) void k_agg(const unsigned short* __restrict__ AB,
    const int* __restrict__ offsets, const int* __restrict__ srcs,
    unsigned short* __restrict__ agg){
  int wave = threadIdx.x >> 6, lane = threadIdx.x & 63;
  int e = blockIdx.x * 4 + wave;
  int g = lane >> 4, d = lane & 15;

  ushort4 bq = *(const ushort4*)(AB + (size_t)e * 128 + 64 + d * 4);
  float b0 = bf2f(bq.x), b1 = bf2f(bq.y), b2 = bf2f(bq.z), b3 = bf2f(bq.w);

  int beg = offsets[e], end = offsets[e + 1];
  float a0 = 0.f, a1 = 0.f, a2 = 0.f, a3 = 0.f;

  int i = beg + g;
  for (; i + 4 < end; i += 8){
    int s0 = srcs[i];
    int s1 = srcs[i + 4];
    ushort4 q0 = *(const ushort4*)(AB + (size_t)s0 * 128 + d * 4);
    ushort4 q1 = *(const ushort4*)(AB + (size_t)s1 * 128 + d * 4);
    a0 += selu_f(bf2f(q0.x) + b0);
    a1 += selu_f(bf2f(q0.y) + b1);
    a2 += selu_f(bf2f(q0.z) + b2);
    a3 += selu_f(bf2f(q0.w) + b3);
    a0 += selu_f(bf2f(q1.x) + b0);
    a1 += selu_f(bf2f(q1.y) + b1);
    a2 += selu_f(bf2f(q1.z) + b2);
    a3 += selu_f(bf2f(q1.w) + b3);
  }
  if (i < end){
    int s0 = srcs[i];
    ushort4 q0 = *(const ushort4*)(AB + (size_t)s0 * 128 + d * 4);
    a0 += selu_f(bf2f(q0.x) + b0);
    a1 += selu_f(bf2f(q0.y) + b1);
    a2 += selu_f(bf2f(q0.z) + b2);
    a3 += selu_f(bf2f(q0.w) + b3);
  }

  a0 += __shfl_xor(a0, 16, 64); a0 += __shfl_xor(a0, 32, 64);
  a1 += __shfl_xor(a1, 16, 64); a1 += __shfl_xor(a1, 32, 64);
  a2 += __shfl_xor(a2, 16, 64); a2 += __shfl_xor(a2, 32, 64);
  a3 += __shfl_xor(a3, 16, 64); a3 += __shfl_xor(a3, 32, 64);

  if (g == 0){
    ushort4 o;
    o.x = f2bf(a0); o.y = f2bf(a1); o.z = f2bf(a2); o.w = f2bf(a3);
    *(ushort4*)(agg + (size_t)e * 64 + d * 4) = o;
  }
}

// Fused GRU (+ optional AB for next iteration).
// h kept fp32 only; bf16 fragments built in-register (numerically identical
// to storing/loading an f2bf copy). hn transposed via per-wave LDS tile to
// become the A operand of the AB GEMM.
template<bool WITH_AB>
__global__ __launch_bounds__(256) void k_fused(const unsigned short* __restrict__ agg,
    const float* __restrict__ h_in, float* __restrict__ h_out,
    const unsigned short* __restrict__ kT, const unsigned short* __restrict__ rkT,
    const unsigned short* __restrict__ WcT,
    const float* __restrict__ bi, const float* __restrict__ br,
    const float* __restrict__ b_msg, unsigned short* __restrict__ AB){
  __shared__ unsigned short lds[4][16][68];
  int wave = threadIdx.x >> 6, lane = threadIdx.x & 63;
  int row0 = (blockIdx.x * 4 + wave) * 16;
  int lr = lane & 15, lg = lane >> 4;

  f32x4 ax[12], ah[12];
  #pragma unroll
  for (int i = 0; i < 12; i++){ ax[i] = (f32x4){0.f,0.f,0.f,0.f}; ah[i] = (f32x4){0.f,0.f,0.f,0.f}; }

  #pragma unroll
  for (int s = 0; s < 2; s++){
    int kb = s * 32 + lg * 8;
    bf16x8 xa = *(const bf16x8*)(agg + (size_t)(row0 + lr) * 64 + kb);
    bf16x8 ha = packbf8(h_in + (size_t)(row0 + lr) * 64 + kb);
    #pragma unroll
    for (int ct = 0; ct < 12; ct++){
      bf16x8 bx = *(const bf16x8*)(kT + (ct * 16 + lr) * 64 + kb);
      ax[ct] = __builtin_amdgcn_mfma_f32_16x16x32_bf16(xa, bx, ax[ct], 0, 0, 0);
    }
    #pragma unroll
    for (int ct = 0; ct < 12; ct++){
      bf16x8 bh = *(const bf16x8*)(rkT + (ct * 16 + lr) * 64 + kb);
      ah[ct] = __builtin_amdgcn_mfma_f32_16x16x32_bf16(ha, bh, ah[ct], 0, 0, 0);
    }
  }

  float hn[4][4];
  #pragma unroll
  for (int jt = 0; jt < 4; jt++){
    int j = jt * 16 + lr;
    float biz = bi[j], bir = bi[64 + j], bih = bi[128 + j];
    float brz = br[j], brr = br[64 + j], brh = br[128 + j];
    #pragma unroll
    for (int q = 0; q < 4; q++){
      int row = row0 + lg * 4 + q;
      float xz = ax[jt][q] + biz,     hz = ah[jt][q] + brz;
      float xr = ax[4 + jt][q] + bir, hr = ah[4 + jt][q] + brr;
      float xh = ax[8 + jt][q] + bih, hh = ah[8 + jt][q] + brh;
      float z = sigmoid_f(xz + hz);
      float r = sigmoid_f(xr + hr);
      float c = tanh_f(xh + r * hh);
      size_t idx = (size_t)row * 64 + j;
      float hold = h_in[idx];
      float v = z * hold + (1.f - z) * c;
      h_out[idx] = v;
      hn[jt][q] = v;
    }
  }

  if (WITH_AB){
    // transpose hn (C/D layout) -> row-major bf16 tile in LDS
    #pragma unroll
    for (int jt = 0; jt < 4; jt++)
      #pragma unroll
      for (int q = 0; q < 4; q++)
        lds[wave][lg * 4 + q][jt * 16 + lr] = f2bf(hn[jt][q]);
    __syncthreads();

    f32x4 acc[8];
    #pragma unroll
    for (int i = 0; i < 8; i++) acc[i] = (f32x4){0.f,0.f,0.f,0.f};
    #pragma unroll
    for (int s = 0; s < 2; s++){
      int kb = s * 32 + lg * 8;
      bf16x8 a = *(const bf16x8*)(&lds[wave][lr][kb]);
      #pragma unroll
      for (int ct = 0; ct < 8; ct++){
        bf16x8 b = *(const bf16x8*)(WcT + (ct * 16 + lr) * 64 + kb);
        acc[ct] = __builtin_amdgcn_mfma_f32_16x16x32_bf16(a, b, acc[ct], 0, 0, 0);
      }
    }
    #pragma unroll
    for (int ct = 0; ct < 8; ct++){
      int col = ct * 16 + lr;
      float bias = (col >= 64) ? b_msg[col - 64] : 0.f;
      #pragma unroll
      for (int q = 0; q < 4; q++){
        int row = row0 + lg * 4 + q;
        AB[(size_t)row * 128 + col] = f2bf(acc[ct][q] + bias);
      }
    }
  }
}

// ---------------- readout ----------------

__global__ __launch_bounds__(256) void k_seg(const float* __restrict__ hf,
    const int* __restrict__ goff, float* __restrict__ gsum){
  int wave = threadIdx.x >> 6, lane = threadIdx.x & 63;
  int g = blockIdx.x * 4 + wave;
  int beg = goff[g], end = goff[g + 1];
  float acc = 0.f;
  for (int e = beg; e < end; e++) acc += hf[(size_t)e * 64 + lane];
  gsum[(size_t)g * 64 + lane] = acc;
}

__global__ __launch_bounds__(256) void k_mlp(const float* __restrict__ gsum,
    const float* __restrict__ W1, const float* __restrict__ b1,
    const float* __restrict__ W2, const float* __restrict__ b2,
    const float* __restrict__ W3, const float* __restrict__ b3,
    float* __restrict__ out){
  __shared__ float sg[64];
  __shared__ float sr1[256];
  __shared__ float sr2[256];
  __shared__ float wsum[4];
  int g = blockIdx.x, t = threadIdx.x;
  if (t < 64) sg[t] = gsum[(size_t)g * 64 + t];
  __syncthreads();
  float a = b1[t];
  #pragma unroll
  for (int k = 0; k < 64; k++) a += sg[k] * W1[k * 256 + t];
  sr1[t] = selu_f(a);
  __syncthreads();
  float b = b2[t];
  for (int k = 0; k < 256; k++) b += sr1[k] * W2[k * 256 + t];
  sr2[t] = selu_f(b);
  __syncthreads();
  float v = sr2[t] * W3[t];
  for (int off = 32; off > 0; off >>= 1) v += __shfl_down(v, off, 64);
  if ((t & 63) == 0) wsum[t >> 6] = v;
  __syncthreads();
  if (t == 0) out[g] = wsum[0] + wsum[1] + wsum[2] + wsum[3] + b3[0];
}

// ---------------- host ----------------

static inline size_t alignup(size_t x){ return (x + 255) & ~(size_t)255; }

extern "C" void kernel_launch(void* const* d_in, const int* in_sizes, int n_in,
                              void* d_out, int out_size, void* d_ws, size_t ws_size,
                              hipStream_t stream) {
  const float* states_action = (const float*)d_in[0];
  const int*   graph_ids     = (const int*)d_in[1];
  const int*   first         = (const int*)d_in[2];
  const int*   second        = (const int*)d_in[3];
  const float* W_msg         = (const float*)d_in[5];
  const float* b_msg         = (const float*)d_in[6];
  const float* gk            = (const float*)d_in[7];
  const float* grk           = (const float*)d_in[8];
  const float* bi            = (const float*)d_in[9];
  const float* br            = (const float*)d_in[10];
  const float* W1            = (const float*)d_in[11];
  const float* b1            = (const float*)d_in[12];
  const float* W2            = (const float*)d_in[13];
  const float* b2            = (const float*)d_in[14];
  const float* W3            = (const float*)d_in[15];
  const float* b3            = (const float*)d_in[16];
  float* out = (float*)d_out;

  char* ws = (char*)d_ws;
  size_t off = 0;
  float*          h_f32  = (float*)(ws + off);          off += alignup((size_t)E_LINKS * 64 * 4);
  unsigned short* aggb   = (unsigned short*)(ws + off); off += alignup((size_t)E_LINKS * 64 * 2);
  unsigned short* AB     = (unsigned short*)(ws + off); off += alignup((size_t)E_LINKS * 128 * 2);
  unsigned short* WcT    = (unsigned short*)(ws + off); off += alignup(128 * 64 * 2);
  unsigned short* kT     = (unsigned short*)(ws + off); off += alignup(192 * 64 * 2);
  unsigned short* rkT    = (unsigned short*)(ws + off); off += alignup(192 * 64 * 2);
  int*            counts = (int*)(ws + off);            off += alignup((size_t)E_LINKS * 4);
  int*            offs   = (int*)(ws + off);            off += alignup(((size_t)E_LINKS + 1) * 4);
  int*            cursor = (int*)(ws + off);            off += alignup((size_t)E_LINKS * 4);
  int*            srcs   = (int*)(ws + off);            off += alignup((size_t)M_PAIRS * 4);
  int*            parts  = (int*)(ws + off);            off += alignup(512 * 4);
  int*            goffs  = (int*)(ws + off);            off += alignup(((size_t)GG + 1) * 4);
  float*          gsum   = (float*)(ws + off);          off += alignup((size_t)GG * 64 * 4);

  dim3 b256(256);

  // CSR preprocessing
  k_zero<<<dim3(E_LINKS / 256), b256, 0, stream>>>(counts);
  k_hist<<<dim3(M_PAIRS / 256), b256, 0, stream>>>(second, counts);
  k_scan_reduce<<<dim3(512), b256, 0, stream>>>(counts, parts);
  k_scan_part<<<dim3(1), dim3(512), 0, stream>>>(parts);
  k_scan_apply<<<dim3(512), b256, 0, stream>>>(counts, parts, offs, cursor);
  k_goffs<<<dim3(E_LINKS / 256), b256, 0, stream>>>(graph_ids, goffs);
  k_scatter<<<dim3(M_PAIRS / 256), b256, 0, stream>>>(first, second, cursor, srcs);

  // weights
  k_prepw<<<dim3(128), b256, 0, stream>>>(W_msg, gk, grk, WcT, kT, rkT);

  // t=0 message precompute from initial h (= states_action)
  k_ab0<<<dim3(E_LINKS / 64), b256, 0, stream>>>(states_action, WcT, b_msg, AB);

  // message passing
  for (int t = 0; t < TITER; t++){
    k_agg<<<dim3(E_LINKS / 4), b256, 0, stream>>>(AB, offs, srcs, aggb);
    const float* h_in = (t == 0) ? states_action : h_f32;
    if (t < TITER - 1)
      k_fused<true><<<dim3(E_LINKS / 64), b256, 0, stream>>>(aggb, h_in, h_f32,
          kT, rkT, WcT, bi, br, b_msg, AB);
    else
      k_fused<false><<<dim3(E_LINKS / 64), b256, 0, stream>>>(aggb, h_in, h_f32,
          kT, rkT, WcT, bi, br, b_msg, AB);
  }

  // readout
  k_seg<<<dim3(GG / 4), b256, 0, stream>>>(h_f32, goffs, gsum);
  k_mlp<<<dim3(GG), b256, 0, stream>>>(gsum, W1, b1, W2, b2, W3, b3, out);
}

// Round 5
// 1154.848 us; speedup vs baseline: 1.9247x; 1.0299x over previous
//
#include <hip/hip_runtime.h>
#include <hip/hip_bf16.h>

// Problem constants (match reference)
#define E_LINKS 131072
#define M_PAIRS 1048576
#define DDIM    64
#define GG      1024
#define RUNITS  256
#define TITER   8

typedef __attribute__((ext_vector_type(8))) short bf16x8;
typedef __attribute__((ext_vector_type(4))) float f32x4;

__device__ inline unsigned short f2bf(float f){
  union { float f; unsigned int u; } v; v.f = f;
  unsigned int u = v.u;
  unsigned int r = (u + 0x7FFFu + ((u >> 16) & 1u)) >> 16;
  return (unsigned short)r;
}
__device__ inline float bf2f(unsigned short u){
  union { unsigned int u; float f; } v; v.u = ((unsigned int)u) << 16; return v.f;
}
__device__ inline float selu_f(float x){
  return x > 0.f ? 1.0507009873554805f * x
                 : 1.7580993408473766f * (__expf(x) - 1.f);
}
__device__ inline float sigmoid_f(float x){ return 1.f / (1.f + __expf(-x)); }
__device__ inline float tanh_f(float x){
  float xc = fminf(fmaxf(x, -15.f), 15.f);
  float e2 = __expf(2.f * xc);
  return (e2 - 1.f) / (e2 + 1.f);
}

// pack 8 contiguous f32 -> bf16x8 fragment
__device__ inline bf16x8 packbf8f(float4 u0, float4 u1){
  bf16x8 r;
  r[0] = (short)f2bf(u0.x); r[1] = (short)f2bf(u0.y);
  r[2] = (short)f2bf(u0.z); r[3] = (short)f2bf(u0.w);
  r[4] = (short)f2bf(u1.x); r[5] = (short)f2bf(u1.y);
  r[6] = (short)f2bf(u1.z); r[7] = (short)f2bf(u1.w);
  return r;
}

// ---------------- preprocessing ----------------

__global__ void k_zero(int* __restrict__ counts){
  int i = blockIdx.x * blockDim.x + threadIdx.x;
  if (i < E_LINKS) counts[i] = 0;
}

__global__ void k_hist(const int* __restrict__ second, int* __restrict__ counts){
  int i = blockIdx.x * blockDim.x + threadIdx.x;
  if (i < M_PAIRS) atomicAdd(&counts[second[i]], 1);
}

__global__ __launch_bounds__(256) void k_scan_reduce(const int* __restrict__ counts,
    int* __restrict__ partials){
  __shared__ int s[256];
  int t = threadIdx.x;
  int i = blockIdx.x * 256 + t;
  s[t] = counts[i];
  __syncthreads();
  #pragma unroll
  for (int off = 128; off > 0; off >>= 1){
    if (t < off) s[t] += s[t + off];
    __syncthreads();
  }
  if (t == 0) partials[blockIdx.x] = s[0];
}

__global__ __launch_bounds__(512) void k_scan_part(int* __restrict__ partials){
  __shared__ int s[512];
  int t = threadIdx.x;
  int v = partials[t];
  s[t] = v;
  __syncthreads();
  for (int off = 1; off < 512; off <<= 1){
    int u = (t >= off) ? s[t - off] : 0;
    __syncthreads();
    s[t] += u;
    __syncthreads();
  }
  partials[t] = s[t] - v;
}

__global__ __launch_bounds__(256) void k_scan_apply(const int* __restrict__ counts,
    const int* __restrict__ partials, int* __restrict__ offsets,
    int* __restrict__ cursor){
  __shared__ int s[256];
  int t = threadIdx.x;
  int i = blockIdx.x * 256 + t;
  int c = counts[i];
  s[t] = c;
  __syncthreads();
  for (int off = 1; off < 256; off <<= 1){
    int u = (t >= off) ? s[t - off] : 0;
    __syncthreads();
    s[t] += u;
    __syncthreads();
  }
  int run = partials[blockIdx.x] + s[t] - c;
  offsets[i] = run;
  cursor[i] = run;
  if (i == E_LINKS - 1) offsets[E_LINKS] = run + c;
}

__global__ void k_goffs(const int* __restrict__ gid, int* __restrict__ goffs){
  int i = blockIdx.x * blockDim.x + threadIdx.x;
  if (i >= E_LINKS) return;
  int g = gid[i];
  int gp = (i == 0) ? -1 : gid[i - 1];
  for (int x = gp + 1; x <= g; x++) goffs[x] = i;
  if (i == E_LINKS - 1){
    for (int x = g + 1; x <= GG; x++) goffs[x] = E_LINKS;
  }
}

__global__ void k_scatter(const int* __restrict__ first, const int* __restrict__ second,
    int* __restrict__ cursor, int* __restrict__ srcs){
  int i = blockIdx.x * blockDim.x + threadIdx.x;
  if (i < M_PAIRS){
    int e = second[i];
    int slot = atomicAdd(&cursor[e], 1);
    srcs[slot] = first[i];
  }
}

// Build transposed bf16 weights + combined biases.
// WzrT[c][k]: c in [0,128) (z cols 0..63, r cols 64..127), k in [0,128):
//   k<64 -> gk[k][c], k>=64 -> grk[k-64][c]
// WxhT[c][k] = gk[k][128+c]; WhhT[c][k] = grk[k][128+c]  (c,k in [0,64))
// WcT[c][k]: c<64 -> W_msg[k][c]; c>=64 -> W_msg[64+k][c-64]
// bzr[c] = bi[c]+br[c]; bxh[c] = bi[128+c]; bhh[c] = br[128+c]
__global__ void k_prepw(const float* __restrict__ W_msg,
    const float* __restrict__ gk, const float* __restrict__ grk,
    const float* __restrict__ bi, const float* __restrict__ br,
    unsigned short* __restrict__ WzrT, unsigned short* __restrict__ WxhT,
    unsigned short* __restrict__ WhhT, unsigned short* __restrict__ WcT,
    float* __restrict__ bzr, float* __restrict__ bxh, float* __restrict__ bhh){
  int i = blockIdx.x * blockDim.x + threadIdx.x;
  if (i < 16384){
    int c = i >> 7, k = i & 127;
    float v = (k < 64) ? gk[k * 192 + c] : grk[(k - 64) * 192 + c];
    WzrT[i] = f2bf(v);
  } else if (i < 20480){
    int j = i - 16384; int c = j >> 6, k = j & 63;
    WxhT[j] = f2bf(gk[k * 192 + 128 + c]);
  } else if (i < 24576){
    int j = i - 20480; int c = j >> 6, k = j & 63;
    WhhT[j] = f2bf(grk[k * 192 + 128 + c]);
  } else if (i < 32768){
    int j = i - 24576; int c = j >> 6, k = j & 63;
    float v = (c < 64) ? W_msg[k * 64 + c] : W_msg[(64 + k) * 64 + (c - 64)];
    WcT[j] = f2bf(v);
  } else if (i < 33024){
    int j = i - 32768;
    if (j < 128) bzr[j] = bi[j] + br[j];
    else if (j < 192) bxh[j - 128] = bi[j];
    else bhh[j - 192] = br[j - 64];
  }
}

// ---------------- main loop kernels ----------------

// AB[E,128] = h[E,64] @ Wc[64,128] (+ b_msg on cols>=64); h read as f32.
__global__ __launch_bounds__(256) void k_ab0(const float* __restrict__ hf,
    const unsigned short* __restrict__ WcT, const float* __restrict__ b_msg,
    unsigned short* __restrict__ AB){
  int wave = threadIdx.x >> 6, lane = threadIdx.x & 63;
  int row0 = (blockIdx.x * 4 + wave) * 16;
  int lr = lane & 15, lg = lane >> 4;
  f32x4 acc[8];
  #pragma unroll
  for (int i = 0; i < 8; i++) acc[i] = (f32x4){0.f, 0.f, 0.f, 0.f};
  #pragma unroll
  for (int s = 0; s < 2; s++){
    int kb = s * 32 + lg * 8;
    const float* p = hf + (size_t)(row0 + lr) * 64 + kb;
    bf16x8 a = packbf8f(*(const float4*)p, *(const float4*)(p + 4));
    #pragma unroll
    for (int ct = 0; ct < 8; ct++){
      bf16x8 b = *(const bf16x8*)(WcT + (ct * 16 + lr) * 64 + kb);
      acc[ct] = __builtin_amdgcn_mfma_f32_16x16x32_bf16(a, b, acc[ct], 0, 0, 0);
    }
  }
  #pragma unroll
  for (int ct = 0; ct < 8; ct++){
    int col = ct * 16 + lr;
    float bias = (col >= 64) ? b_msg[col - 64] : 0.f;
    #pragma unroll
    for (int q = 0; q < 4; q++){
      int row = row0 + lg * 4 + q;
      AB[(size_t)row * 128 + col] = f2bf(acc[ct][q] + bias);
    }
  }
}

// agg[e][:] = sum over incoming msgs: selu(A[src] + B[e])
__global__ __launch_bounds__(256) void k_agg(const unsigned short* __restrict__ AB,
    const int* __restrict__ offsets, const int* __restrict__ srcs,
    unsigned short* __restrict__ agg){
  int wave = threadIdx.x >> 6, lane = threadIdx.x & 63;
  int e = blockIdx.x * 4 + wave;
  int g = lane >> 4, d = lane & 15;

  ushort4 bq = *(const ushort4*)(AB + (size_t)e * 128 + 64 + d * 4);
  float b0 = bf2f(bq.x), b1 = bf2f(bq.y), b2 = bf2f(bq.z), b3 = bf2f(bq.w);

  int beg = offsets[e], end = offsets[e + 1];
  float a0 = 0.f, a1 = 0.f, a2 = 0.f, a3 = 0.f;

  int i = beg + g;
  for (; i + 4 < end; i += 8){
    int s0 = srcs[i];
    int s1 = srcs[i + 4];
    ushort4 q0 = *(const ushort4*)(AB + (size_t)s0 * 128 + d * 4);
    ushort4 q1 = *(const ushort4*)(AB + (size_t)s1 * 128 + d * 4);
    a0 += selu_f(bf2f(q0.x) + b0);
    a1 += selu_f(bf2f(q0.y) + b1);
    a2 += selu_f(bf2f(q0.z) + b2);
    a3 += selu_f(bf2f(q0.w) + b3);
    a0 += selu_f(bf2f(q1.x) + b0);
    a1 += selu_f(bf2f(q1.y) + b1);
    a2 += selu_f(bf2f(q1.z) + b2);
    a3 += selu_f(bf2f(q1.w) + b3);
  }
  if (i < end){
    int s0 = srcs[i];
    ushort4 q0 = *(const ushort4*)(AB + (size_t)s0 * 128 + d * 4);
    a0 += selu_f(bf2f(q0.x) + b0);
    a1 += selu_f(bf2f(q0.y) + b1);
    a2 += selu_f(bf2f(q0.z) + b2);
    a3 += selu_f(bf2f(q0.w) + b3);
  }

  a0 += __shfl_xor(a0, 16, 64); a0 += __shfl_xor(a0, 32, 64);
  a1 += __shfl_xor(a1, 16, 64); a1 += __shfl_xor(a1, 32, 64);
  a2 += __shfl_xor(a2, 16, 64); a2 += __shfl_xor(a2, 32, 64);
  a3 += __shfl_xor(a3, 16, 64); a3 += __shfl_xor(a3, 32, 64);

  if (g == 0){
    ushort4 o;
    o.x = f2bf(a0); o.y = f2bf(a1); o.z = f2bf(a2); o.w = f2bf(a3);
    *(ushort4*)(agg + (size_t)e * 64 + d * 4) = o;
  }
}

// Fused GRU (+ optional AB for next iteration).
// zr gates via ONE combined GEMM over K=128 ([agg|h]); xh/hh separate (K=64).
// h rows stashed in per-wave LDS tile for the `hold` read (no global re-read).
// No __syncthreads needed: all LDS tiles are per-wave.
template<bool WITH_AB>
__global__ __launch_bounds__(256) void k_fused(const unsigned short* __restrict__ agg,
    const float* __restrict__ h_in, float* __restrict__ h_out,
    const unsigned short* __restrict__ WzrT, const unsigned short* __restrict__ WxhT,
    const unsigned short* __restrict__ WhhT, const unsigned short* __restrict__ WcT,
    const float* __restrict__ bzr, const float* __restrict__ bxh,
    const float* __restrict__ bhh,
    const float* __restrict__ b_msg, unsigned short* __restrict__ AB){
  __shared__ float hsh[4][16][68];            // fp32 h rows (2-way bank aliasing only)
  __shared__ unsigned short tsh[4][16][72];   // bf16 hn transpose tile (16B-aligned rows)
  int wave = threadIdx.x >> 6, lane = threadIdx.x & 63;
  int row0 = (blockIdx.x * 4 + wave) * 16;
  int lr = lane & 15, lg = lane >> 4;

  // A fragments over combined K=128: s=0,1 from agg; s=2,3 from h (stash fp32 in LDS)
  bf16x8 az[4];
  #pragma unroll
  for (int s = 0; s < 2; s++){
    int kb = s * 32 + lg * 8;
    az[s] = *(const bf16x8*)(agg + (size_t)(row0 + lr) * 64 + kb);
  }
  #pragma unroll
  for (int s = 2; s < 4; s++){
    int kb = (s - 2) * 32 + lg * 8;
    const float* p = h_in + (size_t)(row0 + lr) * 64 + kb;
    float4 u0 = *(const float4*)p;
    float4 u1 = *(const float4*)(p + 4);
    az[s] = packbf8f(u0, u1);
    *(float4*)(&hsh[wave][lr][kb]) = u0;
    *(float4*)(&hsh[wave][lr][kb + 4]) = u1;
  }

  f32x4 azr[8], axh[4], ahh[4];
  #pragma unroll
  for (int i = 0; i < 8; i++) azr[i] = (f32x4){0.f,0.f,0.f,0.f};
  #pragma unroll
  for (int i = 0; i < 4; i++){ axh[i] = (f32x4){0.f,0.f,0.f,0.f}; ahh[i] = (f32x4){0.f,0.f,0.f,0.f}; }

  #pragma unroll
  for (int s = 0; s < 4; s++){
    int kb = s * 32 + lg * 8;
    #pragma unroll
    for (int ct = 0; ct < 8; ct++){
      bf16x8 b = *(const bf16x8*)(WzrT + (ct * 16 + lr) * 128 + kb);
      azr[ct] = __builtin_amdgcn_mfma_f32_16x16x32_bf16(az[s], b, azr[ct], 0, 0, 0);
    }
  }
  #pragma unroll
  for (int s = 0; s < 2; s++){
    int kb = s * 32 + lg * 8;
    #pragma unroll
    for (int ct = 0; ct < 4; ct++){
      bf16x8 b = *(const bf16x8*)(WxhT + (ct * 16 + lr) * 64 + kb);
      axh[ct] = __builtin_amdgcn_mfma_f32_16x16x32_bf16(az[s], b, axh[ct], 0, 0, 0);
    }
    #pragma unroll
    for (int ct = 0; ct < 4; ct++){
      bf16x8 b = *(const bf16x8*)(WhhT + (ct * 16 + lr) * 64 + kb);
      ahh[ct] = __builtin_amdgcn_mfma_f32_16x16x32_bf16(az[s + 2], b, ahh[ct], 0, 0, 0);
    }
  }

  #pragma unroll
  for (int jt = 0; jt < 4; jt++){
    int j = jt * 16 + lr;
    float bz = bzr[j], brv = bzr[64 + j], bx = bxh[j], bh = bhh[j];
    #pragma unroll
    for (int q = 0; q < 4; q++){
      int rloc = lg * 4 + q;
      float z = sigmoid_f(azr[jt][q] + bz);
      float r = sigmoid_f(azr[4 + jt][q] + brv);
      float c = tanh_f(axh[jt][q] + bx + r * (ahh[jt][q] + bh));
      float hold = hsh[wave][rloc][j];
      float v = z * hold + (1.f - z) * c;
      h_out[(size_t)(row0 + rloc) * 64 + j] = v;
      if (WITH_AB) tsh[wave][rloc][j] = f2bf(v);
    }
  }

  if (WITH_AB){
    f32x4 acc[8];
    #pragma unroll
    for (int i = 0; i < 8; i++) acc[i] = (f32x4){0.f,0.f,0.f,0.f};
    #pragma unroll
    for (int s = 0; s < 2; s++){
      int kb = s * 32 + lg * 8;
      bf16x8 a = *(const bf16x8*)(&tsh[wave][lr][kb]);
      #pragma unroll
      for (int ct = 0; ct < 8; ct++){
        bf16x8 b = *(const bf16x8*)(WcT + (ct * 16 + lr) * 64 + kb);
        acc[ct] = __builtin_amdgcn_mfma_f32_16x16x32_bf16(a, b, acc[ct], 0, 0, 0);
      }
    }
    #pragma unroll
    for (int ct = 0; ct < 8; ct++){
      int col = ct * 16 + lr;
      float bias = (col >= 64) ? b_msg[col - 64] : 0.f;
      #pragma unroll
      for (int q = 0; q < 4; q++){
        int row = row0 + lg * 4 + q;
        AB[(size_t)row * 128 + col] = f2bf(acc[ct][q] + bias);
      }
    }
  }
}

// ---------------- readout ----------------

__global__ __launch_bounds__(256) void k_seg(const float* __restrict__ hf,
    const int* __restrict__ goff, float* __restrict__ gsum){
  int wave = threadIdx.x >> 6, lane = threadIdx.x & 63;
  int g = blockIdx.x * 4 + wave;
  int beg = goff[g], end = goff[g + 1];
  float acc = 0.f;
  for (int e = beg; e < end; e++) acc += hf[(size_t)e * 64 + lane];
  gsum[(size_t)g * 64 + lane] = acc;
}

__global__ __launch_bounds__(256) void k_mlp(const float* __restrict__ gsum,
    const float* __restrict__ W1, const float* __restrict__ b1,
    const float* __restrict__ W2, const float* __restrict__ b2,
    const float* __restrict__ W3, const float* __restrict__ b3,
    float* __restrict__ out){
  __shared__ float sg[64];
  __shared__ float sr1[256];
  __shared__ float sr2[256];
  __shared__ float wsum[4];
  int g = blockIdx.x, t = threadIdx.x;
  if (t < 64) sg[t] = gsum[(size_t)g * 64 + t];
  __syncthreads();
  float a = b1[t];
  #pragma unroll
  for (int k = 0; k < 64; k++) a += sg[k] * W1[k * 256 + t];
  sr1[t] = selu_f(a);
  __syncthreads();
  float b = b2[t];
  for (int k = 0; k < 256; k++) b += sr1[k] * W2[k * 256 + t];
  sr2[t] = selu_f(b);
  __syncthreads();
  float v = sr2[t] * W3[t];
  for (int off = 32; off > 0; off >>= 1) v += __shfl_down(v, off, 64);
  if ((t & 63) == 0) wsum[t >> 6] = v;
  __syncthreads();
  if (t == 0) out[g] = wsum[0] + wsum[1] + wsum[2] + wsum[3] + b3[0];
}

// ---------------- host ----------------

static inline size_t alignup(size_t x){ return (x + 255) & ~(size_t)255; }

extern "C" void kernel_launch(void* const* d_in, const int* in_sizes, int n_in,
                              void* d_out, int out_size, void* d_ws, size_t ws_size,
                              hipStream_t stream) {
  const float* states_action = (const float*)d_in[0];
  const int*   graph_ids     = (const int*)d_in[1];
  const int*   first         = (const int*)d_in[2];
  const int*   second        = (const int*)d_in[3];
  const float* W_msg         = (const float*)d_in[5];
  const float* b_msg         = (const float*)d_in[6];
  const float* gk            = (const float*)d_in[7];
  const float* grk           = (const float*)d_in[8];
  const float* bi            = (const float*)d_in[9];
  const float* br            = (const float*)d_in[10];
  const float* W1            = (const float*)d_in[11];
  const float* b1            = (const float*)d_in[12];
  const float* W2            = (const float*)d_in[13];
  const float* b2            = (const float*)d_in[14];
  const float* W3            = (const float*)d_in[15];
  const float* b3            = (const float*)d_in[16];
  float* out = (float*)d_out;

  char* ws = (char*)d_ws;
  size_t off = 0;
  float*          h_f32  = (float*)(ws + off);          off += alignup((size_t)E_LINKS * 64 * 4);
  unsigned short* aggb   = (unsigned short*)(ws + off); off += alignup((size_t)E_LINKS * 64 * 2);
  unsigned short* AB     = (unsigned short*)(ws + off); off += alignup((size_t)E_LINKS * 128 * 2);
  unsigned short* WzrT   = (unsigned short*)(ws + off); off += alignup(128 * 128 * 2);
  unsigned short* WxhT   = (unsigned short*)(ws + off); off += alignup(64 * 64 * 2);
  unsigned short* WhhT   = (unsigned short*)(ws + off); off += alignup(64 * 64 * 2);
  unsigned short* WcT    = (unsigned short*)(ws + off); off += alignup(128 * 64 * 2);
  float*          bzr    = (float*)(ws + off);          off += alignup(128 * 4);
  float*          bxhv   = (float*)(ws + off);          off += alignup(64 * 4);
  float*          bhhv   = (float*)(ws + off);          off += alignup(64 * 4);
  int*            counts = (int*)(ws + off);            off += alignup((size_t)E_LINKS * 4);
  int*            offs   = (int*)(ws + off);            off += alignup(((size_t)E_LINKS + 1) * 4);
  int*            cursor = (int*)(ws + off);            off += alignup((size_t)E_LINKS * 4);
  int*            srcs   = (int*)(ws + off);            off += alignup((size_t)M_PAIRS * 4);
  int*            parts  = (int*)(ws + off);            off += alignup(512 * 4);
  int*            goffs  = (int*)(ws + off);            off += alignup(((size_t)GG + 1) * 4);
  float*          gsum   = (float*)(ws + off);          off += alignup((size_t)GG * 64 * 4);

  dim3 b256(256);

  // CSR preprocessing
  k_zero<<<dim3(E_LINKS / 256), b256, 0, stream>>>(counts);
  k_hist<<<dim3(M_PAIRS / 256), b256, 0, stream>>>(second, counts);
  k_scan_reduce<<<dim3(512), b256, 0, stream>>>(counts, parts);
  k_scan_part<<<dim3(1), dim3(512), 0, stream>>>(parts);
  k_scan_apply<<<dim3(512), b256, 0, stream>>>(counts, parts, offs, cursor);
  k_goffs<<<dim3(E_LINKS / 256), b256, 0, stream>>>(graph_ids, goffs);
  k_scatter<<<dim3(M_PAIRS / 256), b256, 0, stream>>>(first, second, cursor, srcs);

  // weights (33024 elements total -> 129 blocks)
  k_prepw<<<dim3(129), b256, 0, stream>>>(W_msg, gk, grk, bi, br,
      WzrT, WxhT, WhhT, WcT, bzr, bxhv, bhhv);

  // t=0 message precompute from initial h (= states_action)
  k_ab0<<<dim3(E_LINKS / 64), b256, 0, stream>>>(states_action, WcT, b_msg, AB);

  // message passing
  for (int t = 0; t < TITER; t++){
    k_agg<<<dim3(E_LINKS / 4), b256, 0, stream>>>(AB, offs, srcs, aggb);
    const float* h_in = (t == 0) ? states_action : h_f32;
    if (t < TITER - 1)
      k_fused<true><<<dim3(E_LINKS / 64), b256, 0, stream>>>(aggb, h_in, h_f32,
          WzrT, WxhT, WhhT, WcT, bzr, bxhv, bhhv, b_msg, AB);
    else
      k_fused<false><<<dim3(E_LINKS / 64), b256, 0, stream>>>(aggb, h_in, h_f32,
          WzrT, WxhT, WhhT, WcT, bzr, bxhv, bhhv, b_msg, AB);
  }

  // readout
  k_seg<<<dim3(GG / 4), b256, 0, stream>>>(h_f32, goffs, gsum);
  k_mlp<<<dim3(GG), b256, 0, stream>>>(gsum, W1, b1, W2, b2, W3, b3, out);
}

// Round 6
// 1096.330 us; speedup vs baseline: 2.0274x; 1.0534x over previous
//
#include <hip/hip_runtime.h>
#include <hip/hip_bf16.h>

// Problem constants (match reference)
#define E_LINKS 131072
#define M_PAIRS 1048576
#define DDIM    64
#define GG      1024
#define RUNITS  256
#define TITER   8

typedef __attribute__((ext_vector_type(8))) short bf16x8;
typedef __attribute__((ext_vector_type(4))) float f32x4;
typedef __attribute__((ext_vector_type(16))) float f32x16;

__device__ inline unsigned short f2bf(float f){
  union { float f; unsigned int u; } v; v.f = f;
  unsigned int u = v.u;
  unsigned int r = (u + 0x7FFFu + ((u >> 16) & 1u)) >> 16;
  return (unsigned short)r;
}
__device__ inline float bf2f(unsigned short u){
  union { unsigned int u; float f; } v; v.u = ((unsigned int)u) << 16; return v.f;
}
__device__ inline float selu_f(float x){
  return x > 0.f ? 1.0507009873554805f * x
                 : 1.7580993408473766f * (__expf(x) - 1.f);
}
__device__ inline float sigmoid_f(float x){ return 1.f / (1.f + __expf(-x)); }
__device__ inline float tanh_f(float x){
  float xc = fminf(fmaxf(x, -15.f), 15.f);
  float e2 = __expf(2.f * xc);
  return (e2 - 1.f) / (e2 + 1.f);
}

__device__ inline bf16x8 packbf8f(float4 u0, float4 u1){
  bf16x8 r;
  r[0] = (short)f2bf(u0.x); r[1] = (short)f2bf(u0.y);
  r[2] = (short)f2bf(u0.z); r[3] = (short)f2bf(u0.w);
  r[4] = (short)f2bf(u1.x); r[5] = (short)f2bf(u1.y);
  r[6] = (short)f2bf(u1.z); r[7] = (short)f2bf(u1.w);
  return r;
}

__device__ inline f32x16 zero16(){
  f32x16 v;
  #pragma unroll
  for (int i = 0; i < 16; i++) v[i] = 0.f;
  return v;
}

// ---------------- preprocessing ----------------

__global__ void k_zero(int* __restrict__ counts){
  int i = blockIdx.x * blockDim.x + threadIdx.x;
  if (i < E_LINKS) counts[i] = 0;
}

__global__ void k_hist(const int* __restrict__ second, int* __restrict__ counts){
  int i = blockIdx.x * blockDim.x + threadIdx.x;
  if (i < M_PAIRS) atomicAdd(&counts[second[i]], 1);
}

__global__ __launch_bounds__(256) void k_scan_reduce(const int* __restrict__ counts,
    int* __restrict__ partials){
  __shared__ int s[256];
  int t = threadIdx.x;
  int i = blockIdx.x * 256 + t;
  s[t] = counts[i];
  __syncthreads();
  #pragma unroll
  for (int off = 128; off > 0; off >>= 1){
    if (t < off) s[t] += s[t + off];
    __syncthreads();
  }
  if (t == 0) partials[blockIdx.x] = s[0];
}

__global__ __launch_bounds__(512) void k_scan_part(int* __restrict__ partials){
  __shared__ int s[512];
  int t = threadIdx.x;
  int v = partials[t];
  s[t] = v;
  __syncthreads();
  for (int off = 1; off < 512; off <<= 1){
    int u = (t >= off) ? s[t - off] : 0;
    __syncthreads();
    s[t] += u;
    __syncthreads();
  }
  partials[t] = s[t] - v;
}

__global__ __launch_bounds__(256) void k_scan_apply(const int* __restrict__ counts,
    const int* __restrict__ partials, int* __restrict__ offsets,
    int* __restrict__ cursor){
  __shared__ int s[256];
  int t = threadIdx.x;
  int i = blockIdx.x * 256 + t;
  int c = counts[i];
  s[t] = c;
  __syncthreads();
  for (int off = 1; off < 256; off <<= 1){
    int u = (t >= off) ? s[t - off] : 0;
    __syncthreads();
    s[t] += u;
    __syncthreads();
  }
  int run = partials[blockIdx.x] + s[t] - c;
  offsets[i] = run;
  cursor[i] = run;
  if (i == E_LINKS - 1) offsets[E_LINKS] = run + c;
}

__global__ void k_goffs(const int* __restrict__ gid, int* __restrict__ goffs){
  int i = blockIdx.x * blockDim.x + threadIdx.x;
  if (i >= E_LINKS) return;
  int g = gid[i];
  int gp = (i == 0) ? -1 : gid[i - 1];
  for (int x = gp + 1; x <= g; x++) goffs[x] = i;
  if (i == E_LINKS - 1){
    for (int x = g + 1; x <= GG; x++) goffs[x] = E_LINKS;
  }
}

__global__ void k_scatter(const int* __restrict__ first, const int* __restrict__ second,
    int* __restrict__ cursor, int* __restrict__ srcs){
  int i = blockIdx.x * blockDim.x + threadIdx.x;
  if (i < M_PAIRS){
    int e = second[i];
    int slot = atomicAdd(&cursor[e], 1);
    srcs[slot] = first[i];
  }
}

// Build transposed bf16 weights + combined biases.
// WzrT[c][k]: c in [0,128) (z cols 0..63, r cols 64..127), k in [0,128):
//   k<64 -> gk[k][c], k>=64 -> grk[k-64][c]
// WxhT[c][k] = gk[k][128+c]; WhhT[c][k] = grk[k][128+c]  (c,k in [0,64))
// WcT[c][k]: c<64 -> W_msg[k][c]; c>=64 -> W_msg[64+k][c-64]
// bzr[c] = bi[c]+br[c]; bxh[c] = bi[128+c]; bhh[c] = br[128+c]
__global__ void k_prepw(const float* __restrict__ W_msg,
    const float* __restrict__ gk, const float* __restrict__ grk,
    const float* __restrict__ bi, const float* __restrict__ br,
    unsigned short* __restrict__ WzrT, unsigned short* __restrict__ WxhT,
    unsigned short* __restrict__ WhhT, unsigned short* __restrict__ WcT,
    float* __restrict__ bzr, float* __restrict__ bxh, float* __restrict__ bhh){
  int i = blockIdx.x * blockDim.x + threadIdx.x;
  if (i < 16384){
    int c = i >> 7, k = i & 127;
    float v = (k < 64) ? gk[k * 192 + c] : grk[(k - 64) * 192 + c];
    WzrT[i] = f2bf(v);
  } else if (i < 20480){
    int j = i - 16384; int c = j >> 6, k = j & 63;
    WxhT[j] = f2bf(gk[k * 192 + 128 + c]);
  } else if (i < 24576){
    int j = i - 20480; int c = j >> 6, k = j & 63;
    WhhT[j] = f2bf(grk[k * 192 + 128 + c]);
  } else if (i < 32768){
    int j = i - 24576; int c = j >> 6, k = j & 63;
    float v = (c < 64) ? W_msg[k * 64 + c] : W_msg[(64 + k) * 64 + (c - 64)];
    WcT[j] = f2bf(v);
  } else if (i < 33024){
    int j = i - 32768;
    if (j < 128) bzr[j] = bi[j] + br[j];
    else if (j < 192) bxh[j - 128] = bi[j];
    else bhh[j - 192] = br[j - 64];
  }
}

// ---------------- main loop kernels ----------------

// AB[E,128] = h[E,64] @ Wc[64,128] (+ b_msg on cols>=64); h read as f32.
// 16x16x32 path, runs once.
__global__ __launch_bounds__(256) void k_ab0(const float* __restrict__ hf,
    const unsigned short* __restrict__ WcT, const float* __restrict__ b_msg,
    unsigned short* __restrict__ AB){
  int wave = threadIdx.x >> 6, lane = threadIdx.x & 63;
  int row0 = (blockIdx.x * 4 + wave) * 16;
  int lr = lane & 15, lg = lane >> 4;
  f32x4 acc[8];
  #pragma unroll
  for (int i = 0; i < 8; i++) acc[i] = (f32x4){0.f, 0.f, 0.f, 0.f};
  #pragma unroll
  for (int s = 0; s < 2; s++){
    int kb = s * 32 + lg * 8;
    const float* p = hf + (size_t)(row0 + lr) * 64 + kb;
    bf16x8 a = packbf8f(*(const float4*)p, *(const float4*)(p + 4));
    #pragma unroll
    for (int ct = 0; ct < 8; ct++){
      bf16x8 b = *(const bf16x8*)(WcT + (ct * 16 + lr) * 64 + kb);
      acc[ct] = __builtin_amdgcn_mfma_f32_16x16x32_bf16(a, b, acc[ct], 0, 0, 0);
    }
  }
  #pragma unroll
  for (int ct = 0; ct < 8; ct++){
    int col = ct * 16 + lr;
    float bias = (col >= 64) ? b_msg[col - 64] : 0.f;
    #pragma unroll
    for (int q = 0; q < 4; q++){
      int row = row0 + lg * 4 + q;
      AB[(size_t)row * 128 + col] = f2bf(acc[ct][q] + bias);
    }
  }
}

// agg[e][:] = sum over incoming msgs: selu(A[src] + B[e])
__global__ __launch_bounds__(256) void k_agg(const unsigned short* __restrict__ AB,
    const int* __restrict__ offsets, const int* __restrict__ srcs,
    unsigned short* __restrict__ agg){
  int wave = threadIdx.x >> 6, lane = threadIdx.x & 63;
  int e = blockIdx.x * 4 + wave;
  int g = lane >> 4, d = lane & 15;

  ushort4 bq = *(const ushort4*)(AB + (size_t)e * 128 + 64 + d * 4);
  float b0 = bf2f(bq.x), b1 = bf2f(bq.y), b2 = bf2f(bq.z), b3 = bf2f(bq.w);

  int beg = offsets[e], end = offsets[e + 1];
  float a0 = 0.f, a1 = 0.f, a2 = 0.f, a3 = 0.f;

  int i = beg + g;
  for (; i + 4 < end; i += 8){
    int s0 = srcs[i];
    int s1 = srcs[i + 4];
    ushort4 q0 = *(const ushort4*)(AB + (size_t)s0 * 128 + d * 4);
    ushort4 q1 = *(const ushort4*)(AB + (size_t)s1 * 128 + d * 4);
    a0 += selu_f(bf2f(q0.x) + b0);
    a1 += selu_f(bf2f(q0.y) + b1);
    a2 += selu_f(bf2f(q0.z) + b2);
    a3 += selu_f(bf2f(q0.w) + b3);
    a0 += selu_f(bf2f(q1.x) + b0);
    a1 += selu_f(bf2f(q1.y) + b1);
    a2 += selu_f(bf2f(q1.z) + b2);
    a3 += selu_f(bf2f(q1.w) + b3);
  }
  if (i < end){
    int s0 = srcs[i];
    ushort4 q0 = *(const ushort4*)(AB + (size_t)s0 * 128 + d * 4);
    a0 += selu_f(bf2f(q0.x) + b0);
    a1 += selu_f(bf2f(q0.y) + b1);
    a2 += selu_f(bf2f(q0.z) + b2);
    a3 += selu_f(bf2f(q0.w) + b3);
  }

  a0 += __shfl_xor(a0, 16, 64); a0 += __shfl_xor(a0, 32, 64);
  a1 += __shfl_xor(a1, 16, 64); a1 += __shfl_xor(a1, 32, 64);
  a2 += __shfl_xor(a2, 16, 64); a2 += __shfl_xor(a2, 32, 64);
  a3 += __shfl_xor(a3, 16, 64); a3 += __shfl_xor(a3, 32, 64);

  if (g == 0){
    ushort4 o;
    o.x = f2bf(a0); o.y = f2bf(a1); o.z = f2bf(a2); o.w = f2bf(a3);
    *(ushort4*)(agg + (size_t)e * 64 + d * 4) = o;
  }
}

// Fused GRU (+ optional AB for next iteration), 32 rows/wave via 32x32x16 MFMA.
// Layouts: A/B  row|col = lane&31, k = (lane>>5)*8 + j
//          C/D  col = lane&31, row = (reg&3) + 8*(reg>>2) + 4*(lane>>5)
// Phase order caps VGPR: r-GEMM -> xh/hh GEMMs -> c values -> z-GEMM -> gates.
template<bool WITH_AB>
__global__ __launch_bounds__(256) void k_fused(const unsigned short* __restrict__ agg,
    const float* __restrict__ h_in, float* __restrict__ h_out,
    const unsigned short* __restrict__ WzrT, const unsigned short* __restrict__ WxhT,
    const unsigned short* __restrict__ WhhT, const unsigned short* __restrict__ WcT,
    const float* __restrict__ bzr, const float* __restrict__ bxh,
    const float* __restrict__ bhh,
    const float* __restrict__ b_msg, unsigned short* __restrict__ AB){
  __shared__ float hsh[4][32][68];          // fp32 h rows (hold)
  __shared__ unsigned short tsh[4][32][64]; // bf16 hn, XOR-swizzled 16B blocks
  int wave = threadIdx.x >> 6, lane = threadIdx.x & 63;
  int row0 = (blockIdx.x * 4 + wave) * 32;
  int lc = lane & 31, lh = lane >> 5;

  // ---- A fragments over combined K=128 ([agg | h]) + h stash ----
  bf16x8 az[8];
  const unsigned short* arow = agg + (size_t)(row0 + lc) * 64 + lh * 8;
  #pragma unroll
  for (int s = 0; s < 4; s++) az[s] = *(const bf16x8*)(arow + s * 16);
  const float* hrow = h_in + (size_t)(row0 + lc) * 64 + lh * 8;
  #pragma unroll
  for (int s = 0; s < 4; s++){
    float4 u0 = *(const float4*)(hrow + s * 16);
    float4 u1 = *(const float4*)(hrow + s * 16 + 4);
    az[4 + s] = packbf8f(u0, u1);
    *(float4*)(&hsh[wave][lc][s * 16 + lh * 8]) = u0;
    *(float4*)(&hsh[wave][lc][s * 16 + lh * 8 + 4]) = u1;
  }

  // ---- r-gate GEMM (zr tiles 2,3 -> cols 64..127) ----
  f32x16 ar0 = zero16(), ar1 = zero16();
  #pragma unroll
  for (int s = 0; s < 8; s++){
    const unsigned short* wk = WzrT + lh * 8 + s * 16;
    bf16x8 b2 = *(const bf16x8*)(wk + (size_t)(64 + lc) * 128);
    bf16x8 b3 = *(const bf16x8*)(wk + (size_t)(96 + lc) * 128);
    ar0 = __builtin_amdgcn_mfma_f32_32x32x16_bf16(az[s], b2, ar0, 0, 0, 0);
    ar1 = __builtin_amdgcn_mfma_f32_32x32x16_bf16(az[s], b3, ar1, 0, 0, 0);
  }

  // ---- xh (A=agg) and hh (A=h) GEMMs, N=64 each ----
  f32x16 axh0 = zero16(), axh1 = zero16(), ahh0 = zero16(), ahh1 = zero16();
  #pragma unroll
  for (int s = 0; s < 4; s++){
    const unsigned short* wx = WxhT + lh * 8 + s * 16;
    axh0 = __builtin_amdgcn_mfma_f32_32x32x16_bf16(az[s],
        *(const bf16x8*)(wx + (size_t)lc * 64), axh0, 0, 0, 0);
    axh1 = __builtin_amdgcn_mfma_f32_32x32x16_bf16(az[s],
        *(const bf16x8*)(wx + (size_t)(32 + lc) * 64), axh1, 0, 0, 0);
    const unsigned short* wh = WhhT + lh * 8 + s * 16;
    ahh0 = __builtin_amdgcn_mfma_f32_32x32x16_bf16(az[4 + s],
        *(const bf16x8*)(wh + (size_t)lc * 64), ahh0, 0, 0, 0);
    ahh1 = __builtin_amdgcn_mfma_f32_32x32x16_bf16(az[4 + s],
        *(const bf16x8*)(wh + (size_t)(32 + lc) * 64), ahh1, 0, 0, 0);
  }

  // ---- c values (frees ar/axh/ahh) ----
  float cv[2][16];
  {
    int j0 = lc, j1 = 32 + lc;
    float br0 = bzr[64 + j0], br1 = bzr[64 + j1];
    float bx0 = bxh[j0], bx1 = bxh[j1];
    float bh0 = bhh[j0], bh1 = bhh[j1];
    #pragma unroll
    for (int r = 0; r < 16; r++){
      float rr0 = sigmoid_f(ar0[r] + br0);
      float rr1 = sigmoid_f(ar1[r] + br1);
      cv[0][r] = tanh_f(axh0[r] + bx0 + rr0 * (ahh0[r] + bh0));
      cv[1][r] = tanh_f(axh1[r] + bx1 + rr1 * (ahh1[r] + bh1));
    }
  }

  // ---- z-gate GEMM (zr tiles 0,1 -> cols 0..63) ----
  f32x16 azt0 = zero16(), azt1 = zero16();
  #pragma unroll
  for (int s = 0; s < 8; s++){
    const unsigned short* wk = WzrT + lh * 8 + s * 16;
    bf16x8 b0 = *(const bf16x8*)(wk + (size_t)lc * 128);
    bf16x8 b1 = *(const bf16x8*)(wk + (size_t)(32 + lc) * 128);
    azt0 = __builtin_amdgcn_mfma_f32_32x32x16_bf16(az[s], b0, azt0, 0, 0, 0);
    azt1 = __builtin_amdgcn_mfma_f32_32x32x16_bf16(az[s], b1, azt1, 0, 0, 0);
  }

  // ---- gates, h update, stash hn ----
  {
    int j0 = lc, j1 = 32 + lc;
    float bz0 = bzr[j0], bz1 = bzr[j1];
    #pragma unroll
    for (int r = 0; r < 16; r++){
      int rl = (r & 3) + 8 * (r >> 2) + 4 * lh;
      float z0 = sigmoid_f(azt0[r] + bz0);
      float z1 = sigmoid_f(azt1[r] + bz1);
      float h0 = hsh[wave][rl][j0];
      float h1 = hsh[wave][rl][j1];
      float v0 = z0 * h0 + (1.f - z0) * cv[0][r];
      float v1 = z1 * h1 + (1.f - z1) * cv[1][r];
      h_out[(size_t)(row0 + rl) * 64 + j0] = v0;
      h_out[(size_t)(row0 + rl) * 64 + j1] = v1;
      if (WITH_AB){
        // swizzled store: block' = (j>>3) ^ (rl&7)
        tsh[wave][rl][(((j0 >> 3) ^ (rl & 7)) << 3) + (j0 & 7)] = f2bf(v0);
        tsh[wave][rl][(((j1 >> 3) ^ (rl & 7)) << 3) + (j1 & 7)] = f2bf(v1);
      }
    }
  }

  if (WITH_AB){
    // AB GEMM: M=32, N=128, K=64; A = hn from swizzled tsh
    f32x16 acc[4];
    #pragma unroll
    for (int i = 0; i < 4; i++) acc[i] = zero16();
    #pragma unroll
    for (int s = 0; s < 4; s++){
      int blk = ((s * 2 + lh) ^ (lc & 7)) << 3;
      bf16x8 a = *(const bf16x8*)(&tsh[wave][lc][blk]);
      const unsigned short* wc = WcT + lh * 8 + s * 16;
      #pragma unroll
      for (int ct = 0; ct < 4; ct++){
        bf16x8 b = *(const bf16x8*)(wc + (size_t)(ct * 32 + lc) * 64);
        acc[ct] = __builtin_amdgcn_mfma_f32_32x32x16_bf16(a, b, acc[ct], 0, 0, 0);
      }
    }
    #pragma unroll
    for (int ct = 0; ct < 4; ct++){
      int col = ct * 32 + lc;
      float bias = (col >= 64) ? b_msg[col - 64] : 0.f;
      #pragma unroll
      for (int r = 0; r < 16; r++){
        int rl = (r & 3) + 8 * (r >> 2) + 4 * lh;
        AB[(size_t)(row0 + rl) * 128 + col] = f2bf(acc[ct][r] + bias);
      }
    }
  }
}

// ---------------- readout ----------------

__global__ __launch_bounds__(256) void k_seg(const float* __restrict__ hf,
    const int* __restrict__ goff, float* __restrict__ gsum){
  int wave = threadIdx.x >> 6, lane = threadIdx.x & 63;
  int g = blockIdx.x * 4 + wave;
  int beg = goff[g], end = goff[g + 1];
  float acc = 0.f;
  for (int e = beg; e < end; e++) acc += hf[(size_t)e * 64 + lane];
  gsum[(size_t)g * 64 + lane] = acc;
}

__global__ __launch_bounds__(256) void k_mlp(const float* __restrict__ gsum,
    const float* __restrict__ W1, const float* __restrict__ b1,
    const float* __restrict__ W2, const float* __restrict__ b2,
    const float* __restrict__ W3, const float* __restrict__ b3,
    float* __restrict__ out){
  __shared__ float sg[64];
  __shared__ float sr1[256];
  __shared__ float sr2[256];
  __shared__ float wsum[4];
  int g = blockIdx.x, t = threadIdx.x;
  if (t < 64) sg[t] = gsum[(size_t)g * 64 + t];
  __syncthreads();
  float a = b1[t];
  #pragma unroll
  for (int k = 0; k < 64; k++) a += sg[k] * W1[k * 256 + t];
  sr1[t] = selu_f(a);
  __syncthreads();
  float b = b2[t];
  for (int k = 0; k < 256; k++) b += sr1[k] * W2[k * 256 + t];
  sr2[t] = selu_f(b);
  __syncthreads();
  float v = sr2[t] * W3[t];
  for (int off = 32; off > 0; off >>= 1) v += __shfl_down(v, off, 64);
  if ((t & 63) == 0) wsum[t >> 6] = v;
  __syncthreads();
  if (t == 0) out[g] = wsum[0] + wsum[1] + wsum[2] + wsum[3] + b3[0];
}

// ---------------- host ----------------

static inline size_t alignup(size_t x){ return (x + 255) & ~(size_t)255; }

extern "C" void kernel_launch(void* const* d_in, const int* in_sizes, int n_in,
                              void* d_out, int out_size, void* d_ws, size_t ws_size,
                              hipStream_t stream) {
  const float* states_action = (const float*)d_in[0];
  const int*   graph_ids     = (const int*)d_in[1];
  const int*   first         = (const int*)d_in[2];
  const int*   second        = (const int*)d_in[3];
  const float* W_msg         = (const float*)d_in[5];
  const float* b_msg         = (const float*)d_in[6];
  const float* gk            = (const float*)d_in[7];
  const float* grk           = (const float*)d_in[8];
  const float* bi            = (const float*)d_in[9];
  const float* br            = (const float*)d_in[10];
  const float* W1            = (const float*)d_in[11];
  const float* b1            = (const float*)d_in[12];
  const float* W2            = (const float*)d_in[13];
  const float* b2            = (const float*)d_in[14];
  const float* W3            = (const float*)d_in[15];
  const float* b3            = (const float*)d_in[16];
  float* out = (float*)d_out;

  char* ws = (char*)d_ws;
  size_t off = 0;
  float*          h_f32  = (float*)(ws + off);          off += alignup((size_t)E_LINKS * 64 * 4);
  unsigned short* aggb   = (unsigned short*)(ws + off); off += alignup((size_t)E_LINKS * 64 * 2);
  unsigned short* AB     = (unsigned short*)(ws + off); off += alignup((size_t)E_LINKS * 128 * 2);
  unsigned short* WzrT   = (unsigned short*)(ws + off); off += alignup(128 * 128 * 2);
  unsigned short* WxhT   = (unsigned short*)(ws + off); off += alignup(64 * 64 * 2);
  unsigned short* WhhT   = (unsigned short*)(ws + off); off += alignup(64 * 64 * 2);
  unsigned short* WcT    = (unsigned short*)(ws + off); off += alignup(128 * 64 * 2);
  float*          bzr    = (float*)(ws + off);          off += alignup(128 * 4);
  float*          bxhv   = (float*)(ws + off);          off += alignup(64 * 4);
  float*          bhhv   = (float*)(ws + off);          off += alignup(64 * 4);
  int*            counts = (int*)(ws + off);            off += alignup((size_t)E_LINKS * 4);
  int*            offs   = (int*)(ws + off);            off += alignup(((size_t)E_LINKS + 1) * 4);
  int*            cursor = (int*)(ws + off);            off += alignup((size_t)E_LINKS * 4);
  int*            srcs   = (int*)(ws + off);            off += alignup((size_t)M_PAIRS * 4);
  int*            parts  = (int*)(ws + off);            off += alignup(512 * 4);
  int*            goffs  = (int*)(ws + off);            off += alignup(((size_t)GG + 1) * 4);
  float*          gsum   = (float*)(ws + off);          off += alignup((size_t)GG * 64 * 4);

  dim3 b256(256);

  // CSR preprocessing
  k_zero<<<dim3(E_LINKS / 256), b256, 0, stream>>>(counts);
  k_hist<<<dim3(M_PAIRS / 256), b256, 0, stream>>>(second, counts);
  k_scan_reduce<<<dim3(512), b256, 0, stream>>>(counts, parts);
  k_scan_part<<<dim3(1), dim3(512), 0, stream>>>(parts);
  k_scan_apply<<<dim3(512), b256, 0, stream>>>(counts, parts, offs, cursor);
  k_goffs<<<dim3(E_LINKS / 256), b256, 0, stream>>>(graph_ids, goffs);
  k_scatter<<<dim3(M_PAIRS / 256), b256, 0, stream>>>(first, second, cursor, srcs);

  // weights (33024 elements total -> 129 blocks)
  k_prepw<<<dim3(129), b256, 0, stream>>>(W_msg, gk, grk, bi, br,
      WzrT, WxhT, WhhT, WcT, bzr, bxhv, bhhv);

  // t=0 message precompute from initial h (= states_action)
  k_ab0<<<dim3(E_LINKS / 64), b256, 0, stream>>>(states_action, WcT, b_msg, AB);

  // message passing
  for (int t = 0; t < TITER; t++){
    k_agg<<<dim3(E_LINKS / 4), b256, 0, stream>>>(AB, offs, srcs, aggb);
    const float* h_in = (t == 0) ? states_action : h_f32;
    if (t < TITER - 1)
      k_fused<true><<<dim3(E_LINKS / 128), b256, 0, stream>>>(aggb, h_in, h_f32,
          WzrT, WxhT, WhhT, WcT, bzr, bxhv, bhhv, b_msg, AB);
    else
      k_fused<false><<<dim3(E_LINKS / 128), b256, 0, stream>>>(aggb, h_in, h_f32,
          WzrT, WxhT, WhhT, WcT, bzr, bxhv, bhhv, b_msg, AB);
  }

  // readout
  k_seg<<<dim3(GG / 4), b256, 0, stream>>>(h_f32, goffs, gsum);
  k_mlp<<<dim3(GG), b256, 0, stream>>>(gsum, W1, b1, W2, b2, W3, b3, out);
}

// Round 7
// 1082.178 us; speedup vs baseline: 2.0539x; 1.0131x over previous
//
#include <hip/hip_runtime.h>
#include <hip/hip_bf16.h>

// Problem constants (match reference)
#define E_LINKS 131072
#define M_PAIRS 1048576
#define DDIM    64
#define GG      1024
#define RUNITS  256
#define TITER   8

typedef __attribute__((ext_vector_type(8))) short bf16x8;
typedef __attribute__((ext_vector_type(4))) float f32x4;
typedef __attribute__((ext_vector_type(16))) float f32x16;

__device__ inline unsigned short f2bf(float f){
  union { float f; unsigned int u; } v; v.f = f;
  unsigned int u = v.u;
  unsigned int r = (u + 0x7FFFu + ((u >> 16) & 1u)) >> 16;
  return (unsigned short)r;
}
__device__ inline float bf2f(unsigned short u){
  union { unsigned int u; float f; } v; v.u = ((unsigned int)u) << 16; return v.f;
}
__device__ inline float selu_f(float x){
  return x > 0.f ? 1.0507009873554805f * x
                 : 1.7580993408473766f * (__expf(x) - 1.f);
}
__device__ inline float sigmoid_f(float x){ return 1.f / (1.f + __expf(-x)); }
__device__ inline float tanh_f(float x){
  float xc = fminf(fmaxf(x, -15.f), 15.f);
  float e2 = __expf(2.f * xc);
  return (e2 - 1.f) / (e2 + 1.f);
}

__device__ inline bf16x8 packbf8f(float4 u0, float4 u1){
  bf16x8 r;
  r[0] = (short)f2bf(u0.x); r[1] = (short)f2bf(u0.y);
  r[2] = (short)f2bf(u0.z); r[3] = (short)f2bf(u0.w);
  r[4] = (short)f2bf(u1.x); r[5] = (short)f2bf(u1.y);
  r[6] = (short)f2bf(u1.z); r[7] = (short)f2bf(u1.w);
  return r;
}

__device__ inline f32x16 zero16(){
  f32x16 v;
  #pragma unroll
  for (int i = 0; i < 16; i++) v[i] = 0.f;
  return v;
}

// ---------------- preprocessing ----------------

__global__ void k_zero(int* __restrict__ counts){
  int i = blockIdx.x * blockDim.x + threadIdx.x;
  if (i < E_LINKS) counts[i] = 0;
}

__global__ void k_hist(const int* __restrict__ second, int* __restrict__ counts){
  int i = blockIdx.x * blockDim.x + threadIdx.x;
  if (i < M_PAIRS) atomicAdd(&counts[second[i]], 1);
}

__global__ __launch_bounds__(256) void k_scan_reduce(const int* __restrict__ counts,
    int* __restrict__ partials){
  __shared__ int s[256];
  int t = threadIdx.x;
  int i = blockIdx.x * 256 + t;
  s[t] = counts[i];
  __syncthreads();
  #pragma unroll
  for (int off = 128; off > 0; off >>= 1){
    if (t < off) s[t] += s[t + off];
    __syncthreads();
  }
  if (t == 0) partials[blockIdx.x] = s[0];
}

__global__ __launch_bounds__(512) void k_scan_part(int* __restrict__ partials){
  __shared__ int s[512];
  int t = threadIdx.x;
  int v = partials[t];
  s[t] = v;
  __syncthreads();
  for (int off = 1; off < 512; off <<= 1){
    int u = (t >= off) ? s[t - off] : 0;
    __syncthreads();
    s[t] += u;
    __syncthreads();
  }
  partials[t] = s[t] - v;
}

__global__ __launch_bounds__(256) void k_scan_apply(const int* __restrict__ counts,
    const int* __restrict__ partials, int* __restrict__ offsets,
    int* __restrict__ cursor){
  __shared__ int s[256];
  int t = threadIdx.x;
  int i = blockIdx.x * 256 + t;
  int c = counts[i];
  s[t] = c;
  __syncthreads();
  for (int off = 1; off < 256; off <<= 1){
    int u = (t >= off) ? s[t - off] : 0;
    __syncthreads();
    s[t] += u;
    __syncthreads();
  }
  int run = partials[blockIdx.x] + s[t] - c;
  offsets[i] = run;
  cursor[i] = run;
  if (i == E_LINKS - 1) offsets[E_LINKS] = run + c;
}

__global__ void k_goffs(const int* __restrict__ gid, int* __restrict__ goffs){
  int i = blockIdx.x * blockDim.x + threadIdx.x;
  if (i >= E_LINKS) return;
  int g = gid[i];
  int gp = (i == 0) ? -1 : gid[i - 1];
  for (int x = gp + 1; x <= g; x++) goffs[x] = i;
  if (i == E_LINKS - 1){
    for (int x = g + 1; x <= GG; x++) goffs[x] = E_LINKS;
  }
}

__global__ void k_scatter(const int* __restrict__ first, const int* __restrict__ second,
    int* __restrict__ cursor, int* __restrict__ srcs){
  int i = blockIdx.x * blockDim.x + threadIdx.x;
  if (i < M_PAIRS){
    int e = second[i];
    int slot = atomicAdd(&cursor[e], 1);
    srcs[slot] = first[i];
  }
}

// Build transposed bf16 weights + combined biases.
__global__ void k_prepw(const float* __restrict__ W_msg,
    const float* __restrict__ gk, const float* __restrict__ grk,
    const float* __restrict__ bi, const float* __restrict__ br,
    unsigned short* __restrict__ WzrT, unsigned short* __restrict__ WxhT,
    unsigned short* __restrict__ WhhT, unsigned short* __restrict__ WcT,
    float* __restrict__ bzr, float* __restrict__ bxh, float* __restrict__ bhh){
  int i = blockIdx.x * blockDim.x + threadIdx.x;
  if (i < 16384){
    int c = i >> 7, k = i & 127;
    float v = (k < 64) ? gk[k * 192 + c] : grk[(k - 64) * 192 + c];
    WzrT[i] = f2bf(v);
  } else if (i < 20480){
    int j = i - 16384; int c = j >> 6, k = j & 63;
    WxhT[j] = f2bf(gk[k * 192 + 128 + c]);
  } else if (i < 24576){
    int j = i - 20480; int c = j >> 6, k = j & 63;
    WhhT[j] = f2bf(grk[k * 192 + 128 + c]);
  } else if (i < 32768){
    int j = i - 24576; int c = j >> 6, k = j & 63;
    float v = (c < 64) ? W_msg[k * 64 + c] : W_msg[(64 + k) * 64 + (c - 64)];
    WcT[j] = f2bf(v);
  } else if (i < 33024){
    int j = i - 32768;
    if (j < 128) bzr[j] = bi[j] + br[j];
    else if (j < 192) bxh[j - 128] = bi[j];
    else bhh[j - 192] = br[j - 64];
  }
}

// ---------------- main loop kernels ----------------

// AB[E,128] = h[E,64] @ Wc[64,128] (+ b_msg on cols>=64); h read as f32.
__global__ __launch_bounds__(256) void k_ab0(const float* __restrict__ hf,
    const unsigned short* __restrict__ WcT, const float* __restrict__ b_msg,
    unsigned short* __restrict__ AB){
  int wave = threadIdx.x >> 6, lane = threadIdx.x & 63;
  int row0 = (blockIdx.x * 4 + wave) * 16;
  int lr = lane & 15, lg = lane >> 4;
  f32x4 acc[8];
  #pragma unroll
  for (int i = 0; i < 8; i++) acc[i] = (f32x4){0.f, 0.f, 0.f, 0.f};
  #pragma unroll
  for (int s = 0; s < 2; s++){
    int kb = s * 32 + lg * 8;
    const float* p = hf + (size_t)(row0 + lr) * 64 + kb;
    bf16x8 a = packbf8f(*(const float4*)p, *(const float4*)(p + 4));
    #pragma unroll
    for (int ct = 0; ct < 8; ct++){
      bf16x8 b = *(const bf16x8*)(WcT + (ct * 16 + lr) * 64 + kb);
      acc[ct] = __builtin_amdgcn_mfma_f32_16x16x32_bf16(a, b, acc[ct], 0, 0, 0);
    }
  }
  #pragma unroll
  for (int ct = 0; ct < 8; ct++){
    int col = ct * 16 + lr;
    float bias = (col >= 64) ? b_msg[col - 64] : 0.f;
    #pragma unroll
    for (int q = 0; q < 4; q++){
      int row = row0 + lg * 4 + q;
      AB[(size_t)row * 128 + col] = f2bf(acc[ct][q] + bias);
    }
  }
}

// agg[e][:] = sum over incoming msgs: selu(A[src] + B[e])
__global__ __launch_bounds__(256) void k_agg(const unsigned short* __restrict__ AB,
    const int* __restrict__ offsets, const int* __restrict__ srcs,
    unsigned short* __restrict__ agg){
  int wave = threadIdx.x >> 6, lane = threadIdx.x & 63;
  int e = blockIdx.x * 4 + wave;
  int g = lane >> 4, d = lane & 15;

  ushort4 bq = *(const ushort4*)(AB + (size_t)e * 128 + 64 + d * 4);
  float b0 = bf2f(bq.x), b1 = bf2f(bq.y), b2 = bf2f(bq.z), b3 = bf2f(bq.w);

  int beg = offsets[e], end = offsets[e + 1];
  float a0 = 0.f, a1 = 0.f, a2 = 0.f, a3 = 0.f;

  int i = beg + g;
  for (; i + 4 < end; i += 8){
    int s0 = srcs[i];
    int s1 = srcs[i + 4];
    ushort4 q0 = *(const ushort4*)(AB + (size_t)s0 * 128 + d * 4);
    ushort4 q1 = *(const ushort4*)(AB + (size_t)s1 * 128 + d * 4);
    a0 += selu_f(bf2f(q0.x) + b0);
    a1 += selu_f(bf2f(q0.y) + b1);
    a2 += selu_f(bf2f(q0.z) + b2);
    a3 += selu_f(bf2f(q0.w) + b3);
    a0 += selu_f(bf2f(q1.x) + b0);
    a1 += selu_f(bf2f(q1.y) + b1);
    a2 += selu_f(bf2f(q1.z) + b2);
    a3 += selu_f(bf2f(q1.w) + b3);
  }
  if (i < end){
    int s0 = srcs[i];
    ushort4 q0 = *(const ushort4*)(AB + (size_t)s0 * 128 + d * 4);
    a0 += selu_f(bf2f(q0.x) + b0);
    a1 += selu_f(bf2f(q0.y) + b1);
    a2 += selu_f(bf2f(q0.z) + b2);
    a3 += selu_f(bf2f(q0.w) + b3);
  }

  a0 += __shfl_xor(a0, 16, 64); a0 += __shfl_xor(a0, 32, 64);
  a1 += __shfl_xor(a1, 16, 64); a1 += __shfl_xor(a1, 32, 64);
  a2 += __shfl_xor(a2, 16, 64); a2 += __shfl_xor(a2, 32, 64);
  a3 += __shfl_xor(a3, 16, 64); a3 += __shfl_xor(a3, 32, 64);

  if (g == 0){
    ushort4 o;
    o.x = f2bf(a0); o.y = f2bf(a1); o.z = f2bf(a2); o.w = f2bf(a3);
    *(ushort4*)(agg + (size_t)e * 64 + d * 4) = o;
  }
}

// Fused GRU (+ optional AB), 32 rows/wave via 32x32x16 MFMA.
// Layouts: A/B  row|col = lane&31, k = (lane>>5)*8 + j
//          C/D  col = lane&31, row = (reg&3) + 8*(reg>>2) + 4*(lane>>5)
// LDS: ONLY the 4KB/wave bf16 transpose tile (tsh). hold re-read from global
// (L1-hot; rows were just loaded as fragments by this block).
// Phase order for VGPR<=128: r -> {xh0,hh0}->cv0 -> {xh1,hh1}->cv1 -> z -> gates.
// NOTE: h_in/h_out intentionally NOT __restrict__ (they alias for t>0; the
// in-place update is per-lane read-before-write, compiler must keep order).
template<bool WITH_AB>
__global__ __launch_bounds__(256, 4) void k_fused(const unsigned short* __restrict__ agg,
    const float* h_in, float* h_out,
    const unsigned short* __restrict__ WzrT, const unsigned short* __restrict__ WxhT,
    const unsigned short* __restrict__ WhhT, const unsigned short* __restrict__ WcT,
    const float* __restrict__ bzr, const float* __restrict__ bxh,
    const float* __restrict__ bhh,
    const float* __restrict__ b_msg, unsigned short* __restrict__ AB){
  __shared__ unsigned short tsh[4][32][64]; // bf16 hn, XOR-swizzled 16B blocks
  int wave = threadIdx.x >> 6, lane = threadIdx.x & 63;
  int row0 = (blockIdx.x * 4 + wave) * 32;
  int lc = lane & 31, lh = lane >> 5;

  // ---- A fragments over combined K=128 ([agg | h]) ----
  bf16x8 az[8];
  const unsigned short* arow = agg + (size_t)(row0 + lc) * 64 + lh * 8;
  #pragma unroll
  for (int s = 0; s < 4; s++) az[s] = *(const bf16x8*)(arow + s * 16);
  const float* hrow = h_in + (size_t)(row0 + lc) * 64 + lh * 8;
  #pragma unroll
  for (int s = 0; s < 4; s++){
    float4 u0 = *(const float4*)(hrow + s * 16);
    float4 u1 = *(const float4*)(hrow + s * 16 + 4);
    az[4 + s] = packbf8f(u0, u1);
  }

  // ---- r-gate GEMM (zr tiles 2,3 -> cols 64..127) ----
  f32x16 ar0 = zero16(), ar1 = zero16();
  #pragma unroll
  for (int s = 0; s < 8; s++){
    const unsigned short* wk = WzrT + lh * 8 + s * 16;
    bf16x8 b2 = *(const bf16x8*)(wk + (size_t)(64 + lc) * 128);
    bf16x8 b3 = *(const bf16x8*)(wk + (size_t)(96 + lc) * 128);
    ar0 = __builtin_amdgcn_mfma_f32_32x32x16_bf16(az[s], b2, ar0, 0, 0, 0);
    ar1 = __builtin_amdgcn_mfma_f32_32x32x16_bf16(az[s], b3, ar1, 0, 0, 0);
  }

  float cv[2][16];

  // ---- cols 0..31: xh0 (A=agg), hh0 (A=h) -> cv[0] ----
  {
    f32x16 axh = zero16(), ahh = zero16();
    #pragma unroll
    for (int s = 0; s < 4; s++){
      const unsigned short* wx = WxhT + lh * 8 + s * 16;
      axh = __builtin_amdgcn_mfma_f32_32x32x16_bf16(az[s],
          *(const bf16x8*)(wx + (size_t)lc * 64), axh, 0, 0, 0);
      const unsigned short* wh = WhhT + lh * 8 + s * 16;
      ahh = __builtin_amdgcn_mfma_f32_32x32x16_bf16(az[4 + s],
          *(const bf16x8*)(wh + (size_t)lc * 64), ahh, 0, 0, 0);
    }
    float brv = bzr[64 + lc], bx = bxh[lc], bh = bhh[lc];
    #pragma unroll
    for (int r = 0; r < 16; r++){
      float rr = sigmoid_f(ar0[r] + brv);
      cv[0][r] = tanh_f(axh[r] + bx + rr * (ahh[r] + bh));
    }
  }

  // ---- cols 32..63: xh1, hh1 -> cv[1] ----
  {
    f32x16 axh = zero16(), ahh = zero16();
    #pragma unroll
    for (int s = 0; s < 4; s++){
      const unsigned short* wx = WxhT + lh * 8 + s * 16;
      axh = __builtin_amdgcn_mfma_f32_32x32x16_bf16(az[s],
          *(const bf16x8*)(wx + (size_t)(32 + lc) * 64), axh, 0, 0, 0);
      const unsigned short* wh = WhhT + lh * 8 + s * 16;
      ahh = __builtin_amdgcn_mfma_f32_32x32x16_bf16(az[4 + s],
          *(const bf16x8*)(wh + (size_t)(32 + lc) * 64), ahh, 0, 0, 0);
    }
    float brv = bzr[64 + 32 + lc], bx = bxh[32 + lc], bh = bhh[32 + lc];
    #pragma unroll
    for (int r = 0; r < 16; r++){
      float rr = sigmoid_f(ar1[r] + brv);
      cv[1][r] = tanh_f(axh[r] + bx + rr * (ahh[r] + bh));
    }
  }

  // ---- z-gate GEMM (zr tiles 0,1 -> cols 0..63) ----
  f32x16 azt0 = zero16(), azt1 = zero16();
  #pragma unroll
  for (int s = 0; s < 8; s++){
    const unsigned short* wk = WzrT + lh * 8 + s * 16;
    bf16x8 b0 = *(const bf16x8*)(wk + (size_t)lc * 128);
    bf16x8 b1 = *(const bf16x8*)(wk + (size_t)(32 + lc) * 128);
    azt0 = __builtin_amdgcn_mfma_f32_32x32x16_bf16(az[s], b0, azt0, 0, 0, 0);
    azt1 = __builtin_amdgcn_mfma_f32_32x32x16_bf16(az[s], b1, azt1, 0, 0, 0);
  }

  // ---- gates, h update (hold from global, L1-hot), stash hn ----
  {
    int j0 = lc, j1 = 32 + lc;
    float bz0 = bzr[j0], bz1 = bzr[j1];
    #pragma unroll
    for (int r = 0; r < 16; r++){
      int rl = (r & 3) + 8 * (r >> 2) + 4 * lh;
      size_t base = (size_t)(row0 + rl) * 64;
      float h0 = h_in[base + j0];
      float h1 = h_in[base + j1];
      float z0 = sigmoid_f(azt0[r] + bz0);
      float z1 = sigmoid_f(azt1[r] + bz1);
      float v0 = z0 * h0 + (1.f - z0) * cv[0][r];
      float v1 = z1 * h1 + (1.f - z1) * cv[1][r];
      h_out[base + j0] = v0;
      h_out[base + j1] = v1;
      if (WITH_AB){
        tsh[wave][rl][(((j0 >> 3) ^ (rl & 7)) << 3) + (j0 & 7)] = f2bf(v0);
        tsh[wave][rl][(((j1 >> 3) ^ (rl & 7)) << 3) + (j1 & 7)] = f2bf(v1);
      }
    }
  }

  if (WITH_AB){
    // AB GEMM: M=32, N=128, K=64; A = hn from swizzled tsh
    f32x16 acc[4];
    #pragma unroll
    for (int i = 0; i < 4; i++) acc[i] = zero16();
    #pragma unroll
    for (int s = 0; s < 4; s++){
      int blk = ((s * 2 + lh) ^ (lc & 7)) << 3;
      bf16x8 a = *(const bf16x8*)(&tsh[wave][lc][blk]);
      const unsigned short* wc = WcT + lh * 8 + s * 16;
      #pragma unroll
      for (int ct = 0; ct < 4; ct++){
        bf16x8 b = *(const bf16x8*)(wc + (size_t)(ct * 32 + lc) * 64);
        acc[ct] = __builtin_amdgcn_mfma_f32_32x32x16_bf16(a, b, acc[ct], 0, 0, 0);
      }
    }
    #pragma unroll
    for (int ct = 0; ct < 4; ct++){
      int col = ct * 32 + lc;
      float bias = (col >= 64) ? b_msg[col - 64] : 0.f;
      #pragma unroll
      for (int r = 0; r < 16; r++){
        int rl = (r & 3) + 8 * (r >> 2) + 4 * lh;
        AB[(size_t)(row0 + rl) * 128 + col] = f2bf(acc[ct][r] + bias);
      }
    }
  }
}

// ---------------- readout ----------------

__global__ __launch_bounds__(256) void k_seg(const float* __restrict__ hf,
    const int* __restrict__ goff, float* __restrict__ gsum){
  int wave = threadIdx.x >> 6, lane = threadIdx.x & 63;
  int g = blockIdx.x * 4 + wave;
  int beg = goff[g], end = goff[g + 1];
  float acc = 0.f;
  for (int e = beg; e < end; e++) acc += hf[(size_t)e * 64 + lane];
  gsum[(size_t)g * 64 + lane] = acc;
}

__global__ __launch_bounds__(256) void k_mlp(const float* __restrict__ gsum,
    const float* __restrict__ W1, const float* __restrict__ b1,
    const float* __restrict__ W2, const float* __restrict__ b2,
    const float* __restrict__ W3, const float* __restrict__ b3,
    float* __restrict__ out){
  __shared__ float sg[64];
  __shared__ float sr1[256];
  __shared__ float sr2[256];
  __shared__ float wsum[4];
  int g = blockIdx.x, t = threadIdx.x;
  if (t < 64) sg[t] = gsum[(size_t)g * 64 + t];
  __syncthreads();
  float a = b1[t];
  #pragma unroll
  for (int k = 0; k < 64; k++) a += sg[k] * W1[k * 256 + t];
  sr1[t] = selu_f(a);
  __syncthreads();
  float b = b2[t];
  for (int k = 0; k < 256; k++) b += sr1[k] * W2[k * 256 + t];
  sr2[t] = selu_f(b);
  __syncthreads();
  float v = sr2[t] * W3[t];
  for (int off = 32; off > 0; off >>= 1) v += __shfl_down(v, off, 64);
  if ((t & 63) == 0) wsum[t >> 6] = v;
  __syncthreads();
  if (t == 0) out[g] = wsum[0] + wsum[1] + wsum[2] + wsum[3] + b3[0];
}

// ---------------- host ----------------

static inline size_t alignup(size_t x){ return (x + 255) & ~(size_t)255; }

extern "C" void kernel_launch(void* const* d_in, const int* in_sizes, int n_in,
                              void* d_out, int out_size, void* d_ws, size_t ws_size,
                              hipStream_t stream) {
  const float* states_action = (const float*)d_in[0];
  const int*   graph_ids     = (const int*)d_in[1];
  const int*   first         = (const int*)d_in[2];
  const int*   second        = (const int*)d_in[3];
  const float* W_msg         = (const float*)d_in[5];
  const float* b_msg         = (const float*)d_in[6];
  const float* gk            = (const float*)d_in[7];
  const float* grk           = (const float*)d_in[8];
  const float* bi            = (const float*)d_in[9];
  const float* br            = (const float*)d_in[10];
  const float* W1            = (const float*)d_in[11];
  const float* b1            = (const float*)d_in[12];
  const float* W2            = (const float*)d_in[13];
  const float* b2            = (const float*)d_in[14];
  const float* W3            = (const float*)d_in[15];
  const float* b3            = (const float*)d_in[16];
  float* out = (float*)d_out;

  char* ws = (char*)d_ws;
  size_t off = 0;
  float*          h_f32  = (float*)(ws + off);          off += alignup((size_t)E_LINKS * 64 * 4);
  unsigned short* aggb   = (unsigned short*)(ws + off); off += alignup((size_t)E_LINKS * 64 * 2);
  unsigned short* AB     = (unsigned short*)(ws + off); off += alignup((size_t)E_LINKS * 128 * 2);
  unsigned short* WzrT   = (unsigned short*)(ws + off); off += alignup(128 * 128 * 2);
  unsigned short* WxhT   = (unsigned short*)(ws + off); off += alignup(64 * 64 * 2);
  unsigned short* WhhT   = (unsigned short*)(ws + off); off += alignup(64 * 64 * 2);
  unsigned short* WcT    = (unsigned short*)(ws + off); off += alignup(128 * 64 * 2);
  float*          bzr    = (float*)(ws + off);          off += alignup(128 * 4);
  float*          bxhv   = (float*)(ws + off);          off += alignup(64 * 4);
  float*          bhhv   = (float*)(ws + off);          off += alignup(64 * 4);
  int*            counts = (int*)(ws + off);            off += alignup((size_t)E_LINKS * 4);
  int*            offs   = (int*)(ws + off);            off += alignup(((size_t)E_LINKS + 1) * 4);
  int*            cursor = (int*)(ws + off);            off += alignup((size_t)E_LINKS * 4);
  int*            srcs   = (int*)(ws + off);            off += alignup((size_t)M_PAIRS * 4);
  int*            parts  = (int*)(ws + off);            off += alignup(512 * 4);
  int*            goffs  = (int*)(ws + off);            off += alignup(((size_t)GG + 1) * 4);
  float*          gsum   = (float*)(ws + off);          off += alignup((size_t)GG * 64 * 4);

  dim3 b256(256);

  // CSR preprocessing
  k_zero<<<dim3(E_LINKS / 256), b256, 0, stream>>>(counts);
  k_hist<<<dim3(M_PAIRS / 256), b256, 0, stream>>>(second, counts);
  k_scan_reduce<<<dim3(512), b256, 0, stream>>>(counts, parts);
  k_scan_part<<<dim3(1), dim3(512), 0, stream>>>(parts);
  k_scan_apply<<<dim3(512), b256, 0, stream>>>(counts, parts, offs, cursor);
  k_goffs<<<dim3(E_LINKS / 256), b256, 0, stream>>>(graph_ids, goffs);
  k_scatter<<<dim3(M_PAIRS / 256), b256, 0, stream>>>(first, second, cursor, srcs);

  // weights (33024 elements total -> 129 blocks)
  k_prepw<<<dim3(129), b256, 0, stream>>>(W_msg, gk, grk, bi, br,
      WzrT, WxhT, WhhT, WcT, bzr, bxhv, bhhv);

  // t=0 message precompute from initial h (= states_action)
  k_ab0<<<dim3(E_LINKS / 64), b256, 0, stream>>>(states_action, WcT, b_msg, AB);

  // message passing
  for (int t = 0; t < TITER; t++){
    k_agg<<<dim3(E_LINKS / 4), b256, 0, stream>>>(AB, offs, srcs, aggb);
    const float* h_in = (t == 0) ? states_action : h_f32;
    if (t < TITER - 1)
      k_fused<true><<<dim3(E_LINKS / 128), b256, 0, stream>>>(aggb, h_in, h_f32,
          WzrT, WxhT, WhhT, WcT, bzr, bxhv, bhhv, b_msg, AB);
    else
      k_fused<false><<<dim3(E_LINKS / 128), b256, 0, stream>>>(aggb, h_in, h_f32,
          WzrT, WxhT, WhhT, WcT, bzr, bxhv, bhhv, b_msg, AB);
  }

  // readout
  k_seg<<<dim3(GG / 4), b256, 0, stream>>>(h_f32, goffs, gsum);
  k_mlp<<<dim3(GG), b256, 0, stream>>>(gsum, W1, b1, W2, b2, W3, b3, out);
}

// Round 8
// 989.719 us; speedup vs baseline: 2.2458x; 1.0934x over previous
//
#include <hip/hip_runtime.h>
#include <hip/hip_bf16.h>

// Problem constants (match reference)
#define E_LINKS 131072
#define M_PAIRS 1048576
#define DDIM    64
#define GG      1024
#define RUNITS  256
#define TITER   8

typedef __attribute__((ext_vector_type(8))) short bf16x8;
typedef __attribute__((ext_vector_type(4))) float f32x4;
typedef __attribute__((ext_vector_type(16))) float f32x16;

__device__ inline unsigned short f2bf(float f){
  union { float f; unsigned int u; } v; v.f = f;
  unsigned int u = v.u;
  unsigned int r = (u + 0x7FFFu + ((u >> 16) & 1u)) >> 16;
  return (unsigned short)r;
}
__device__ inline float bf2f(unsigned short u){
  union { unsigned int u; float f; } v; v.u = ((unsigned int)u) << 16; return v.f;
}
__device__ inline float selu_f(float x){
  return x > 0.f ? 1.0507009873554805f * x
                 : 1.7580993408473766f * (__expf(x) - 1.f);
}
__device__ inline float sigmoid_f(float x){ return 1.f / (1.f + __expf(-x)); }
__device__ inline float tanh_f(float x){
  float xc = fminf(fmaxf(x, -15.f), 15.f);
  float e2 = __expf(2.f * xc);
  return (e2 - 1.f) / (e2 + 1.f);
}

__device__ inline bf16x8 packbf8f(float4 u0, float4 u1){
  bf16x8 r;
  r[0] = (short)f2bf(u0.x); r[1] = (short)f2bf(u0.y);
  r[2] = (short)f2bf(u0.z); r[3] = (short)f2bf(u0.w);
  r[4] = (short)f2bf(u1.x); r[5] = (short)f2bf(u1.y);
  r[6] = (short)f2bf(u1.z); r[7] = (short)f2bf(u1.w);
  return r;
}

__device__ inline f32x16 zero16(){
  f32x16 v;
  #pragma unroll
  for (int i = 0; i < 16; i++) v[i] = 0.f;
  return v;
}

// ---------------- preprocessing ----------------

__global__ void k_zero(int* __restrict__ counts){
  int i = blockIdx.x * blockDim.x + threadIdx.x;
  if (i < E_LINKS) counts[i] = 0;
}

__global__ void k_hist(const int* __restrict__ second, int* __restrict__ counts){
  int i = blockIdx.x * blockDim.x + threadIdx.x;
  if (i < M_PAIRS) atomicAdd(&counts[second[i]], 1);
}

__global__ __launch_bounds__(256) void k_scan_reduce(const int* __restrict__ counts,
    int* __restrict__ partials){
  __shared__ int s[256];
  int t = threadIdx.x;
  int i = blockIdx.x * 256 + t;
  s[t] = counts[i];
  __syncthreads();
  #pragma unroll
  for (int off = 128; off > 0; off >>= 1){
    if (t < off) s[t] += s[t + off];
    __syncthreads();
  }
  if (t == 0) partials[blockIdx.x] = s[0];
}

__global__ __launch_bounds__(512) void k_scan_part(int* __restrict__ partials){
  __shared__ int s[512];
  int t = threadIdx.x;
  int v = partials[t];
  s[t] = v;
  __syncthreads();
  for (int off = 1; off < 512; off <<= 1){
    int u = (t >= off) ? s[t - off] : 0;
    __syncthreads();
    s[t] += u;
    __syncthreads();
  }
  partials[t] = s[t] - v;
}

__global__ __launch_bounds__(256) void k_scan_apply(const int* __restrict__ counts,
    const int* __restrict__ partials, int* __restrict__ offsets,
    int* __restrict__ cursor){
  __shared__ int s[256];
  int t = threadIdx.x;
  int i = blockIdx.x * 256 + t;
  int c = counts[i];
  s[t] = c;
  __syncthreads();
  for (int off = 1; off < 256; off <<= 1){
    int u = (t >= off) ? s[t - off] : 0;
    __syncthreads();
    s[t] += u;
    __syncthreads();
  }
  int run = partials[blockIdx.x] + s[t] - c;
  offsets[i] = run;
  cursor[i] = run;
  if (i == E_LINKS - 1) offsets[E_LINKS] = run + c;
}

__global__ void k_goffs(const int* __restrict__ gid, int* __restrict__ goffs){
  int i = blockIdx.x * blockDim.x + threadIdx.x;
  if (i >= E_LINKS) return;
  int g = gid[i];
  int gp = (i == 0) ? -1 : gid[i - 1];
  for (int x = gp + 1; x <= g; x++) goffs[x] = i;
  if (i == E_LINKS - 1){
    for (int x = g + 1; x <= GG; x++) goffs[x] = E_LINKS;
  }
}

__global__ void k_scatter(const int* __restrict__ first, const int* __restrict__ second,
    int* __restrict__ cursor, int* __restrict__ srcs){
  int i = blockIdx.x * blockDim.x + threadIdx.x;
  if (i < M_PAIRS){
    int e = second[i];
    int slot = atomicAdd(&cursor[e], 1);
    srcs[slot] = first[i];
  }
}

// Build transposed bf16 weights + combined biases.
__global__ void k_prepw(const float* __restrict__ W_msg,
    const float* __restrict__ gk, const float* __restrict__ grk,
    const float* __restrict__ bi, const float* __restrict__ br,
    unsigned short* __restrict__ WzrT, unsigned short* __restrict__ WxhT,
    unsigned short* __restrict__ WhhT, unsigned short* __restrict__ WcT,
    float* __restrict__ bzr, float* __restrict__ bxh, float* __restrict__ bhh){
  int i = blockIdx.x * blockDim.x + threadIdx.x;
  if (i < 16384){
    int c = i >> 7, k = i & 127;
    float v = (k < 64) ? gk[k * 192 + c] : grk[(k - 64) * 192 + c];
    WzrT[i] = f2bf(v);
  } else if (i < 20480){
    int j = i - 16384; int c = j >> 6, k = j & 63;
    WxhT[j] = f2bf(gk[k * 192 + 128 + c]);
  } else if (i < 24576){
    int j = i - 20480; int c = j >> 6, k = j & 63;
    WhhT[j] = f2bf(grk[k * 192 + 128 + c]);
  } else if (i < 32768){
    int j = i - 24576; int c = j >> 6, k = j & 63;
    float v = (c < 64) ? W_msg[k * 64 + c] : W_msg[(64 + k) * 64 + (c - 64)];
    WcT[j] = f2bf(v);
  } else if (i < 33024){
    int j = i - 32768;
    if (j < 128) bzr[j] = bi[j] + br[j];
    else if (j < 192) bxh[j - 128] = bi[j];
    else bhh[j - 192] = br[j - 64];
  }
}

// ---------------- main loop kernels ----------------

// AB[E,128] = h[E,64] @ Wc[64,128] (+ b_msg on cols>=64); h read as f32.
__global__ __launch_bounds__(256) void k_ab0(const float* __restrict__ hf,
    const unsigned short* __restrict__ WcT, const float* __restrict__ b_msg,
    unsigned short* __restrict__ AB){
  int wave = threadIdx.x >> 6, lane = threadIdx.x & 63;
  int row0 = (blockIdx.x * 4 + wave) * 16;
  int lr = lane & 15, lg = lane >> 4;
  f32x4 acc[8];
  #pragma unroll
  for (int i = 0; i < 8; i++) acc[i] = (f32x4){0.f, 0.f, 0.f, 0.f};
  #pragma unroll
  for (int s = 0; s < 2; s++){
    int kb = s * 32 + lg * 8;
    const float* p = hf + (size_t)(row0 + lr) * 64 + kb;
    bf16x8 a = packbf8f(*(const float4*)p, *(const float4*)(p + 4));
    #pragma unroll
    for (int ct = 0; ct < 8; ct++){
      bf16x8 b = *(const bf16x8*)(WcT + (ct * 16 + lr) * 64 + kb);
      acc[ct] = __builtin_amdgcn_mfma_f32_16x16x32_bf16(a, b, acc[ct], 0, 0, 0);
    }
  }
  #pragma unroll
  for (int ct = 0; ct < 8; ct++){
    int col = ct * 16 + lr;
    float bias = (col >= 64) ? b_msg[col - 64] : 0.f;
    #pragma unroll
    for (int q = 0; q < 4; q++){
      int row = row0 + lg * 4 + q;
      AB[(size_t)row * 128 + col] = f2bf(acc[ct][q] + bias);
    }
  }
}

// agg[e][:] = sum over incoming msgs: selu(A[src] + B[e])
__global__ __launch_bounds__(256) void k_agg(const unsigned short* __restrict__ AB,
    const int* __restrict__ offsets, const int* __restrict__ srcs,
    unsigned short* __restrict__ agg){
  int wave = threadIdx.x >> 6, lane = threadIdx.x & 63;
  int e = blockIdx.x * 4 + wave;
  int g = lane >> 4, d = lane & 15;

  ushort4 bq = *(const ushort4*)(AB + (size_t)e * 128 + 64 + d * 4);
  float b0 = bf2f(bq.x), b1 = bf2f(bq.y), b2 = bf2f(bq.z), b3 = bf2f(bq.w);

  int beg = offsets[e], end = offsets[e + 1];
  float a0 = 0.f, a1 = 0.f, a2 = 0.f, a3 = 0.f;

  int i = beg + g;
  for (; i + 4 < end; i += 8){
    int s0 = srcs[i];
    int s1 = srcs[i + 4];
    ushort4 q0 = *(const ushort4*)(AB + (size_t)s0 * 128 + d * 4);
    ushort4 q1 = *(const ushort4*)(AB + (size_t)s1 * 128 + d * 4);
    a0 += selu_f(bf2f(q0.x) + b0);
    a1 += selu_f(bf2f(q0.y) + b1);
    a2 += selu_f(bf2f(q0.z) + b2);
    a3 += selu_f(bf2f(q0.w) + b3);
    a0 += selu_f(bf2f(q1.x) + b0);
    a1 += selu_f(bf2f(q1.y) + b1);
    a2 += selu_f(bf2f(q1.z) + b2);
    a3 += selu_f(bf2f(q1.w) + b3);
  }
  if (i < end){
    int s0 = srcs[i];
    ushort4 q0 = *(const ushort4*)(AB + (size_t)s0 * 128 + d * 4);
    a0 += selu_f(bf2f(q0.x) + b0);
    a1 += selu_f(bf2f(q0.y) + b1);
    a2 += selu_f(bf2f(q0.z) + b2);
    a3 += selu_f(bf2f(q0.w) + b3);
  }

  a0 += __shfl_xor(a0, 16, 64); a0 += __shfl_xor(a0, 32, 64);
  a1 += __shfl_xor(a1, 16, 64); a1 += __shfl_xor(a1, 32, 64);
  a2 += __shfl_xor(a2, 16, 64); a2 += __shfl_xor(a2, 32, 64);
  a3 += __shfl_xor(a3, 16, 64); a3 += __shfl_xor(a3, 32, 64);

  if (g == 0){
    ushort4 o;
    o.x = f2bf(a0); o.y = f2bf(a1); o.z = f2bf(a2); o.w = f2bf(a3);
    *(ushort4*)(agg + (size_t)e * 64 + d * 4) = o;
  }
}

// Fused GRU (+ optional AB), 32 rows/wave via 32x32x16 MFMA.
// Layouts: A/B  row|col = lane&31, k = (lane>>5)*8 + j
//          C/D  col = lane&31, row = (reg&3) + 8*(reg>>2) + 4*(lane>>5)
// LDS: per-wave fp32 hold tile hsh[32][68] (8.7KB), REUSED (union) as the
// bf16 transpose tile tsh[32][64] after holds are consumed. Phase split:
//   GEMMs -> read all holds (compute v into regs) -> __syncthreads -> write
//   h_out + tsh -> AB GEMM. The barrier makes the aliasing safe.
// LDS/block = 34816 -> 4 blocks/CU; VGPR ~64 -> occupancy ~16 waves/CU.
template<bool WITH_AB>
__global__ __launch_bounds__(256, 4) void k_fused(const unsigned short* __restrict__ agg,
    const float* h_in, float* h_out,
    const unsigned short* __restrict__ WzrT, const unsigned short* __restrict__ WxhT,
    const unsigned short* __restrict__ WhhT, const unsigned short* __restrict__ WcT,
    const float* __restrict__ bzr, const float* __restrict__ bxh,
    const float* __restrict__ bhh,
    const float* __restrict__ b_msg, unsigned short* __restrict__ AB){
  __shared__ float hsh[4][32][68];   // 34816B; tail-reused as tsh
  int wave = threadIdx.x >> 6, lane = threadIdx.x & 63;
  int row0 = (blockIdx.x * 4 + wave) * 32;
  int lc = lane & 31, lh = lane >> 5;
  unsigned short* tsh = (unsigned short*)&hsh[wave][0][0]; // [32][64] bf16, swizzled

  // ---- A fragments over combined K=128 ([agg | h]) + fp32 hold stash ----
  bf16x8 az[8];
  const unsigned short* arow = agg + (size_t)(row0 + lc) * 64 + lh * 8;
  #pragma unroll
  for (int s = 0; s < 4; s++) az[s] = *(const bf16x8*)(arow + s * 16);
  const float* hrow = h_in + (size_t)(row0 + lc) * 64 + lh * 8;
  #pragma unroll
  for (int s = 0; s < 4; s++){
    float4 u0 = *(const float4*)(hrow + s * 16);
    float4 u1 = *(const float4*)(hrow + s * 16 + 4);
    az[4 + s] = packbf8f(u0, u1);
    *(float4*)(&hsh[wave][lc][s * 16 + lh * 8]) = u0;
    *(float4*)(&hsh[wave][lc][s * 16 + lh * 8 + 4]) = u1;
  }

  // ---- r-gate GEMM (zr tiles 2,3 -> cols 64..127) ----
  f32x16 ar0 = zero16(), ar1 = zero16();
  #pragma unroll
  for (int s = 0; s < 8; s++){
    const unsigned short* wk = WzrT + lh * 8 + s * 16;
    bf16x8 b2 = *(const bf16x8*)(wk + (size_t)(64 + lc) * 128);
    bf16x8 b3 = *(const bf16x8*)(wk + (size_t)(96 + lc) * 128);
    ar0 = __builtin_amdgcn_mfma_f32_32x32x16_bf16(az[s], b2, ar0, 0, 0, 0);
    ar1 = __builtin_amdgcn_mfma_f32_32x32x16_bf16(az[s], b3, ar1, 0, 0, 0);
  }

  float cv[2][16];

  // ---- cols 0..31: xh0 (A=agg), hh0 (A=h) -> cv[0] ----
  {
    f32x16 axh = zero16(), ahh = zero16();
    #pragma unroll
    for (int s = 0; s < 4; s++){
      const unsigned short* wx = WxhT + lh * 8 + s * 16;
      axh = __builtin_amdgcn_mfma_f32_32x32x16_bf16(az[s],
          *(const bf16x8*)(wx + (size_t)lc * 64), axh, 0, 0, 0);
      const unsigned short* wh = WhhT + lh * 8 + s * 16;
      ahh = __builtin_amdgcn_mfma_f32_32x32x16_bf16(az[4 + s],
          *(const bf16x8*)(wh + (size_t)lc * 64), ahh, 0, 0, 0);
    }
    float brv = bzr[64 + lc], bx = bxh[lc], bh = bhh[lc];
    #pragma unroll
    for (int r = 0; r < 16; r++){
      float rr = sigmoid_f(ar0[r] + brv);
      cv[0][r] = tanh_f(axh[r] + bx + rr * (ahh[r] + bh));
    }
  }

  // ---- cols 32..63: xh1, hh1 -> cv[1] ----
  {
    f32x16 axh = zero16(), ahh = zero16();
    #pragma unroll
    for (int s = 0; s < 4; s++){
      const unsigned short* wx = WxhT + lh * 8 + s * 16;
      axh = __builtin_amdgcn_mfma_f32_32x32x16_bf16(az[s],
          *(const bf16x8*)(wx + (size_t)(32 + lc) * 64), axh, 0, 0, 0);
      const unsigned short* wh = WhhT + lh * 8 + s * 16;
      ahh = __builtin_amdgcn_mfma_f32_32x32x16_bf16(az[4 + s],
          *(const bf16x8*)(wh + (size_t)(32 + lc) * 64), ahh, 0, 0, 0);
    }
    float brv = bzr[64 + 32 + lc], bx = bxh[32 + lc], bh = bhh[32 + lc];
    #pragma unroll
    for (int r = 0; r < 16; r++){
      float rr = sigmoid_f(ar1[r] + brv);
      cv[1][r] = tanh_f(axh[r] + bx + rr * (ahh[r] + bh));
    }
  }

  // ---- z-gate GEMM (zr tiles 0,1 -> cols 0..63) ----
  f32x16 azt0 = zero16(), azt1 = zero16();
  #pragma unroll
  for (int s = 0; s < 8; s++){
    const unsigned short* wk = WzrT + lh * 8 + s * 16;
    bf16x8 b0 = *(const bf16x8*)(wk + (size_t)lc * 128);
    bf16x8 b1 = *(const bf16x8*)(wk + (size_t)(32 + lc) * 128);
    azt0 = __builtin_amdgcn_mfma_f32_32x32x16_bf16(az[s], b0, azt0, 0, 0, 0);
    azt1 = __builtin_amdgcn_mfma_f32_32x32x16_bf16(az[s], b1, azt1, 0, 0, 0);
  }

  // ---- phase 1: read holds from hsh, fold z -> final v (into cv) ----
  {
    float bz0 = bzr[lc], bz1 = bzr[32 + lc];
    #pragma unroll
    for (int r = 0; r < 16; r++){
      int rl = (r & 3) + 8 * (r >> 2) + 4 * lh;
      float h0 = hsh[wave][rl][lc];
      float h1 = hsh[wave][rl][32 + lc];
      float z0 = sigmoid_f(azt0[r] + bz0);
      float z1 = sigmoid_f(azt1[r] + bz1);
      cv[0][r] = z0 * h0 + (1.f - z0) * cv[0][r];
      cv[1][r] = z1 * h1 + (1.f - z1) * cv[1][r];
    }
  }

  __syncthreads();   // all hsh reads complete before tsh overwrites the space

  // ---- phase 2: write h_out (global) + tsh (LDS, swizzled) ----
  {
    int j0 = lc, j1 = 32 + lc;
    #pragma unroll
    for (int r = 0; r < 16; r++){
      int rl = (r & 3) + 8 * (r >> 2) + 4 * lh;
      size_t base = (size_t)(row0 + rl) * 64;
      h_out[base + j0] = cv[0][r];
      h_out[base + j1] = cv[1][r];
      if (WITH_AB){
        tsh[rl * 64 + (((j0 >> 3) ^ (rl & 7)) << 3) + (j0 & 7)] = f2bf(cv[0][r]);
        tsh[rl * 64 + (((j1 >> 3) ^ (rl & 7)) << 3) + (j1 & 7)] = f2bf(cv[1][r]);
      }
    }
  }

  if (WITH_AB){
    // AB GEMM: M=32, N=128, K=64; A = hn from swizzled tsh
    f32x16 acc[4];
    #pragma unroll
    for (int i = 0; i < 4; i++) acc[i] = zero16();
    #pragma unroll
    for (int s = 0; s < 4; s++){
      int blk = ((s * 2 + lh) ^ (lc & 7)) << 3;
      bf16x8 a = *(const bf16x8*)(&tsh[lc * 64 + blk]);
      const unsigned short* wc = WcT + lh * 8 + s * 16;
      #pragma unroll
      for (int ct = 0; ct < 4; ct++){
        bf16x8 b = *(const bf16x8*)(wc + (size_t)(ct * 32 + lc) * 64);
        acc[ct] = __builtin_amdgcn_mfma_f32_32x32x16_bf16(a, b, acc[ct], 0, 0, 0);
      }
    }
    #pragma unroll
    for (int ct = 0; ct < 4; ct++){
      int col = ct * 32 + lc;
      float bias = (col >= 64) ? b_msg[col - 64] : 0.f;
      #pragma unroll
      for (int r = 0; r < 16; r++){
        int rl = (r & 3) + 8 * (r >> 2) + 4 * lh;
        AB[(size_t)(row0 + rl) * 128 + col] = f2bf(acc[ct][r] + bias);
      }
    }
  }
}

// ---------------- readout ----------------

__global__ __launch_bounds__(256) void k_seg(const float* __restrict__ hf,
    const int* __restrict__ goff, float* __restrict__ gsum){
  int wave = threadIdx.x >> 6, lane = threadIdx.x & 63;
  int g = blockIdx.x * 4 + wave;
  int beg = goff[g], end = goff[g + 1];
  float acc = 0.f;
  for (int e = beg; e < end; e++) acc += hf[(size_t)e * 64 + lane];
  gsum[(size_t)g * 64 + lane] = acc;
}

__global__ __launch_bounds__(256) void k_mlp(const float* __restrict__ gsum,
    const float* __restrict__ W1, const float* __restrict__ b1,
    const float* __restrict__ W2, const float* __restrict__ b2,
    const float* __restrict__ W3, const float* __restrict__ b3,
    float* __restrict__ out){
  __shared__ float sg[64];
  __shared__ float sr1[256];
  __shared__ float sr2[256];
  __shared__ float wsum[4];
  int g = blockIdx.x, t = threadIdx.x;
  if (t < 64) sg[t] = gsum[(size_t)g * 64 + t];
  __syncthreads();
  float a = b1[t];
  #pragma unroll
  for (int k = 0; k < 64; k++) a += sg[k] * W1[k * 256 + t];
  sr1[t] = selu_f(a);
  __syncthreads();
  float b = b2[t];
  for (int k = 0; k < 256; k++) b += sr1[k] * W2[k * 256 + t];
  sr2[t] = selu_f(b);
  __syncthreads();
  float v = sr2[t] * W3[t];
  for (int off = 32; off > 0; off >>= 1) v += __shfl_down(v, off, 64);
  if ((t & 63) == 0) wsum[t >> 6] = v;
  __syncthreads();
  if (t == 0) out[g] = wsum[0] + wsum[1] + wsum[2] + wsum[3] + b3[0];
}

// ---------------- host ----------------

static inline size_t alignup(size_t x){ return (x + 255) & ~(size_t)255; }

extern "C" void kernel_launch(void* const* d_in, const int* in_sizes, int n_in,
                              void* d_out, int out_size, void* d_ws, size_t ws_size,
                              hipStream_t stream) {
  const float* states_action = (const float*)d_in[0];
  const int*   graph_ids     = (const int*)d_in[1];
  const int*   first         = (const int*)d_in[2];
  const int*   second        = (const int*)d_in[3];
  const float* W_msg         = (const float*)d_in[5];
  const float* b_msg         = (const float*)d_in[6];
  const float* gk            = (const float*)d_in[7];
  const float* grk           = (const float*)d_in[8];
  const float* bi            = (const float*)d_in[9];
  const float* br            = (const float*)d_in[10];
  const float* W1            = (const float*)d_in[11];
  const float* b1            = (const float*)d_in[12];
  const float* W2            = (const float*)d_in[13];
  const float* b2            = (const float*)d_in[14];
  const float* W3            = (const float*)d_in[15];
  const float* b3            = (const float*)d_in[16];
  float* out = (float*)d_out;

  char* ws = (char*)d_ws;
  size_t off = 0;
  float*          h_f32  = (float*)(ws + off);          off += alignup((size_t)E_LINKS * 64 * 4);
  unsigned short* aggb   = (unsigned short*)(ws + off); off += alignup((size_t)E_LINKS * 64 * 2);
  unsigned short* AB     = (unsigned short*)(ws + off); off += alignup((size_t)E_LINKS * 128 * 2);
  unsigned short* WzrT   = (unsigned short*)(ws + off); off += alignup(128 * 128 * 2);
  unsigned short* WxhT   = (unsigned short*)(ws + off); off += alignup(64 * 64 * 2);
  unsigned short* WhhT   = (unsigned short*)(ws + off); off += alignup(64 * 64 * 2);
  unsigned short* WcT    = (unsigned short*)(ws + off); off += alignup(128 * 64 * 2);
  float*          bzr    = (float*)(ws + off);          off += alignup(128 * 4);
  float*          bxhv   = (float*)(ws + off);          off += alignup(64 * 4);
  float*          bhhv   = (float*)(ws + off);          off += alignup(64 * 4);
  int*            counts = (int*)(ws + off);            off += alignup((size_t)E_LINKS * 4);
  int*            offs   = (int*)(ws + off);            off += alignup(((size_t)E_LINKS + 1) * 4);
  int*            cursor = (int*)(ws + off);            off += alignup((size_t)E_LINKS * 4);
  int*            srcs   = (int*)(ws + off);            off += alignup((size_t)M_PAIRS * 4);
  int*            parts  = (int*)(ws + off);            off += alignup(512 * 4);
  int*            goffs  = (int*)(ws + off);            off += alignup(((size_t)GG + 1) * 4);
  float*          gsum   = (float*)(ws + off);          off += alignup((size_t)GG * 64 * 4);

  dim3 b256(256);

  // CSR preprocessing
  k_zero<<<dim3(E_LINKS / 256), b256, 0, stream>>>(counts);
  k_hist<<<dim3(M_PAIRS / 256), b256, 0, stream>>>(second, counts);
  k_scan_reduce<<<dim3(512), b256, 0, stream>>>(counts, parts);
  k_scan_part<<<dim3(1), dim3(512), 0, stream>>>(parts);
  k_scan_apply<<<dim3(512), b256, 0, stream>>>(counts, parts, offs, cursor);
  k_goffs<<<dim3(E_LINKS / 256), b256, 0, stream>>>(graph_ids, goffs);
  k_scatter<<<dim3(M_PAIRS / 256), b256, 0, stream>>>(first, second, cursor, srcs);

  // weights (33024 elements total -> 129 blocks)
  k_prepw<<<dim3(129), b256, 0, stream>>>(W_msg, gk, grk, bi, br,
      WzrT, WxhT, WhhT, WcT, bzr, bxhv, bhhv);

  // t=0 message precompute from initial h (= states_action)
  k_ab0<<<dim3(E_LINKS / 64), b256, 0, stream>>>(states_action, WcT, b_msg, AB);

  // message passing
  for (int t = 0; t < TITER; t++){
    k_agg<<<dim3(E_LINKS / 4), b256, 0, stream>>>(AB, offs, srcs, aggb);
    const float* h_in = (t == 0) ? states_action : h_f32;
    if (t < TITER - 1)
      k_fused<true><<<dim3(E_LINKS / 128), b256, 0, stream>>>(aggb, h_in, h_f32,
          WzrT, WxhT, WhhT, WcT, bzr, bxhv, bhhv, b_msg, AB);
    else
      k_fused<false><<<dim3(E_LINKS / 128), b256, 0, stream>>>(aggb, h_in, h_f32,
          WzrT, WxhT, WhhT, WcT, bzr, bxhv, bhhv, b_msg, AB);
  }

  // readout
  k_seg<<<dim3(GG / 4), b256, 0, stream>>>(h_f32, goffs, gsum);
  k_mlp<<<dim3(GG), b256, 0, stream>>>(gsum, W1, b1, W2, b2, W3, b3, out);
}